// Round 4
// baseline (362.077 us; speedup 1.0000x reference)
//
#include <hip/hip_runtime.h>

#define B_ 4
#define N_ 2048
#define R_ (B_ * N_)      // 8192 rows
#define HID_ 256
#define EMB_ 64
#define IN_DIM_ 70
#define H_ 4
#define HEAD_ 64
#define FFN_ 512
#define LAYERS_ 4

typedef __attribute__((ext_vector_type(8))) short short8;
typedef __attribute__((ext_vector_type(4))) float f32x4;
typedef unsigned short ushort;

static __device__ __forceinline__ ushort f2bf(float f) {
    unsigned u = __builtin_bit_cast(unsigned, f);
    u += 0x7fffu + ((u >> 16) & 1u);   // RNE
    return (ushort)(u >> 16);
}
static __device__ __forceinline__ float bf2f(ushort u) {
    unsigned x = ((unsigned)u) << 16;
    return __builtin_bit_cast(float, x);
}

#define GLOAD_LDS16(g, l)                                              \
    __builtin_amdgcn_global_load_lds(                                  \
        (const __attribute__((address_space(1))) void*)(g),            \
        (__attribute__((address_space(3))) void*)(l), 16, 0, 0)

// ---------------------------------------------------------------------------
// Pack all weights to bf16, transposed [c][k] layout, in one kernel.
// Segments: Wvt 262144 | Wat 262144 | W1t 524288 | W2t 524288 | Wo1t 65536
// ---------------------------------------------------------------------------
__global__ __launch_bounds__(256) void pack_weights(const float* __restrict__ valW,
                                                    const float* __restrict__ attnW,
                                                    const float* __restrict__ ffnW1,
                                                    const float* __restrict__ ffnW2,
                                                    const float* __restrict__ outW1,
                                                    ushort* __restrict__ wp) {
    int idx = blockIdx.x * 256 + threadIdx.x;
    float v;
    if (idx < 262144) {
        int l = idx >> 16, c = (idx >> 8) & 255, k = idx & 255;
        v = valW[((l * 4 + (c >> 6)) * 256 + k) * 64 + (c & 63)];
    } else if (idx < 524288) {
        int i2 = idx - 262144;
        int l = i2 >> 16, c = (i2 >> 8) & 255, k = i2 & 255;
        v = attnW[l * 65536 + k * 256 + c];
    } else if (idx < 1048576) {
        int i2 = idx - 524288;
        int l = i2 >> 17, c = (i2 >> 8) & 511, k = i2 & 255;
        v = ffnW1[l * 131072 + k * 512 + c];
    } else if (idx < 1572864) {
        int i2 = idx - 1048576;
        int l = i2 >> 17, c = (i2 >> 9) & 255, k = i2 & 511;
        v = ffnW2[l * 131072 + k * 256 + c];
    } else {
        int i2 = idx - 1572864;
        int c = i2 >> 8, k = i2 & 255;
        v = outW1[k * 256 + c];
    }
    wp[idx] = f2bf(v);
}

// ---------------------------------------------------------------------------
// Input MLP: feats = relu(concat @ in_W + in_b); dual write fp32 + bf16
// ---------------------------------------------------------------------------
__global__ __launch_bounds__(256) void input_mlp(const float* __restrict__ xc,
                                                 const float* __restrict__ emb,
                                                 const float* __restrict__ lat,
                                                 const float* __restrict__ W,
                                                 const float* __restrict__ b,
                                                 float* __restrict__ feats,
                                                 ushort* __restrict__ featsb) {
    __shared__ float xr[8][IN_DIM_ + 2];
    int t = threadIdx.x;
    int row0 = blockIdx.x * 8;
    for (int idx = t; idx < 8 * IN_DIM_; idx += 256) {
        int r = idx / IN_DIM_, f = idx % IN_DIM_;
        int rr = row0 + r;
        float v;
        if (f < 3)       v = xc[rr * 3 + f];
        else if (f < 67) v = emb[rr * EMB_ + (f - 3)];
        else             v = lat[rr * 3 + (f - 67)];
        xr[r][f] = v;
    }
    __syncthreads();
    float acc[8] = {0.f, 0.f, 0.f, 0.f, 0.f, 0.f, 0.f, 0.f};
    for (int f = 0; f < IN_DIM_; ++f) {
        float w = W[f * HID_ + t];
#pragma unroll
        for (int r = 0; r < 8; ++r) acc[r] += xr[r][f] * w;
    }
    float bb = b[t];
#pragma unroll
    for (int r = 0; r < 8; ++r) {
        float v = fmaxf(acc[r] + bb, 0.f);
        feats[(row0 + r) * HID_ + t] = v;
        featsb[(row0 + r) * HID_ + t] = f2bf(v);
    }
}

// ---------------------------------------------------------------------------
// MFMA bf16 GEMM, double-buffered K-loop. Block = 16 rows x 256 cols,
// 256 threads = 4 waves. Wave w: cols w*64.. (N_rep=4).
// MODE 1: +bias, relu -> bf16 out            (FFN1; COLS may be 512)
// MODE 2: +bias,+resid,LN -> fp32 + bf16 out (attn-proj, FFN2)
// MODE 3: +bias -> transposed bf16 Vt[c][n]  (V-proj)
// MODE 4: +bias, relu, then @W2+b2 -> fp32 d_out (final, fused out-proj)
// ---------------------------------------------------------------------------
template <int KD, int COLS, int MODE>
__global__ __launch_bounds__(256) void gemmM(const ushort* __restrict__ A,
                                             const ushort* __restrict__ Bt,
                                             const float* __restrict__ bias,
                                             const float* __restrict__ resid,
                                             const float* __restrict__ lng,
                                             const float* __restrict__ lnb,
                                             ushort* __restrict__ outb,
                                             float* __restrict__ outf) {
    __shared__ __align__(16) char lds[69632];   // As[2]:4KB | Ws[2]:64KB
    int t = threadIdx.x;
    int l = t & 63, w = t >> 6;
    int lr = l & 15, g = l >> 4;
    int row0 = blockIdx.x * 16;
    int cbase = blockIdx.y * 256;
    f32x4 acc[4] = {};

    const ushort* srcA = A + (size_t)(row0 + (t >> 3)) * KD + (((t & 7) ^ ((t >> 3) & 7)) << 3);
    const ushort* srcB[8];
#pragma unroll
    for (int q = 0; q < 8; ++q) {
        int cl = q * 32 + (t >> 3);
        srcB[q] = Bt + (size_t)(cbase + cl) * KD + (((t & 7) ^ (cl & 7)) << 3);
    }

    auto STAGE = [&](int buf) {
        if (t < 128) GLOAD_LDS16(srcA, lds + buf * 2048 + t * 16);
#pragma unroll
        for (int q = 0; q < 8; ++q)
            GLOAD_LDS16(srcB[q], lds + 4096 + buf * 32768 + q * 4096 + t * 16);
        srcA += 64;
#pragma unroll
        for (int q = 0; q < 8; ++q) srcB[q] += 64;
    };

    int sw_a = (lr & 7) << 4;
    int aoff = lr * 128;
    constexpr int CH = KD / 64;

    STAGE(0);
#pragma unroll
    for (int c = 0; c < CH; ++c) {
        __syncthreads();            // drains STAGE(c); prev compute done
        if (c + 1 < CH) STAGE((c + 1) & 1);
        const char* As = lds + (c & 1) * 2048;
        const char* Ws = lds + 4096 + (c & 1) * 32768;

        short8 a0 = *(const short8*)(As + aoff + ((g * 16) ^ sw_a));
        short8 a1 = *(const short8*)(As + aoff + ((64 + g * 16) ^ sw_a));
#pragma unroll
        for (int n = 0; n < 4; ++n) {
            int cc = w * 64 + n * 16 + lr;
            const char* cb = Ws + cc * 128;
            int sw = (cc & 7) << 4;
            short8 b0 = *(const short8*)(cb + ((g * 16) ^ sw));
            short8 b1 = *(const short8*)(cb + ((64 + g * 16) ^ sw));
            acc[n] = __builtin_amdgcn_mfma_f32_16x16x32_bf16(a0, b0, acc[n], 0, 0, 0);
            acc[n] = __builtin_amdgcn_mfma_f32_16x16x32_bf16(a1, b1, acc[n], 0, 0, 0);
        }
    }
    __syncthreads();   // before LDS reuse in epilogues

    if constexpr (MODE == 1) {
#pragma unroll
        for (int n = 0; n < 4; ++n) {
            int c = w * 64 + n * 16 + lr;
            float bi = bias[cbase + c];
#pragma unroll
            for (int r = 0; r < 4; ++r) {
                int row = row0 + g * 4 + r;
                outb[(size_t)row * COLS + cbase + c] = f2bf(fmaxf(acc[n][r] + bi, 0.f));
            }
        }
    } else if constexpr (MODE == 2) {
        float* red1 = (float*)lds;          // [16][4]
        float* red2 = (float*)(lds + 512);
        float vals[4][4];
        float s1[4] = {0.f, 0.f, 0.f, 0.f}, s2[4] = {0.f, 0.f, 0.f, 0.f};
#pragma unroll
        for (int n = 0; n < 4; ++n) {
            int c = w * 64 + n * 16 + lr;
            float bi = bias[c];
#pragma unroll
            for (int r = 0; r < 4; ++r) {
                int row = row0 + g * 4 + r;
                float v = acc[n][r] + bi + resid[(size_t)row * 256 + c];
                vals[n][r] = v;
                s1[r] += v;
                s2[r] += v * v;
            }
        }
#pragma unroll
        for (int off = 1; off < 16; off <<= 1) {
#pragma unroll
            for (int r = 0; r < 4; ++r) {
                s1[r] += __shfl_xor(s1[r], off, 64);
                s2[r] += __shfl_xor(s2[r], off, 64);
            }
        }
        if (lr == 0) {
#pragma unroll
            for (int r = 0; r < 4; ++r) {
                red1[(g * 4 + r) * 4 + w] = s1[r];
                red2[(g * 4 + r) * 4 + w] = s2[r];
            }
        }
        __syncthreads();
        float mu[4], rstd[4];
#pragma unroll
        for (int r = 0; r < 4; ++r) {
            int rr = g * 4 + r;
            float m1 = red1[rr * 4] + red1[rr * 4 + 1] + red1[rr * 4 + 2] + red1[rr * 4 + 3];
            float m2 = red2[rr * 4] + red2[rr * 4 + 1] + red2[rr * 4 + 2] + red2[rr * 4 + 3];
            mu[r] = m1 * (1.f / 256.f);
            float var = m2 * (1.f / 256.f) - mu[r] * mu[r];
            rstd[r] = rsqrtf(var + 1e-5f);
        }
#pragma unroll
        for (int n = 0; n < 4; ++n) {
            int c = w * 64 + n * 16 + lr;
            float gg = lng[c], bb = lnb[c];
#pragma unroll
            for (int r = 0; r < 4; ++r) {
                int row = row0 + g * 4 + r;
                float o = (vals[n][r] - mu[r]) * rstd[r] * gg + bb;
                outf[(size_t)row * 256 + c] = o;
                outb[(size_t)row * 256 + c] = f2bf(o);
            }
        }
    } else if constexpr (MODE == 3) {
        ushort(*Ts)[24] = (ushort(*)[24])lds;   // [256][24]
#pragma unroll
        for (int n = 0; n < 4; ++n) {
            int c = w * 64 + n * 16 + lr;
            float bi = bias[c];
#pragma unroll
            for (int r = 0; r < 4; ++r)
                Ts[c][g * 4 + r] = f2bf(acc[n][r] + bi);
        }
        __syncthreads();
        {
            int c = t;
            int b = row0 >> 11;
            int n0 = row0 & 2047;
            ushort* dst = outb + ((size_t)(b * 256 + c)) * 2048 + n0;
            uint4 v0 = *(uint4*)&Ts[c][0];
            uint4 v1 = *(uint4*)&Ts[c][8];
            *(uint4*)dst = v0;
            *(uint4*)(dst + 8) = v1;
        }
    } else {  // MODE 4
        const float* W2 = resid;    // [256][3]
        const float* b2 = lng;      // [3]
        ushort(*Ts)[264] = (ushort(*)[264])lds;  // [16][264]
#pragma unroll
        for (int n = 0; n < 4; ++n) {
            int c = w * 64 + n * 16 + lr;
            float bi = bias[c];
#pragma unroll
            for (int r = 0; r < 4; ++r)
                Ts[g * 4 + r][c] = f2bf(fmaxf(acc[n][r] + bi, 0.f));
        }
        __syncthreads();
        int row = t >> 4, s = t & 15;
        float p0 = 0.f, p1 = 0.f, p2 = 0.f;
#pragma unroll
        for (int e = 0; e < 16; ++e) {
            float x = bf2f(Ts[row][s * 16 + e]);
            const float* wr = &W2[(s * 16 + e) * 3];
            p0 += x * wr[0];
            p1 += x * wr[1];
            p2 += x * wr[2];
        }
#pragma unroll
        for (int off = 1; off < 16; off <<= 1) {
            p0 += __shfl_xor(p0, off, 64);
            p1 += __shfl_xor(p1, off, 64);
            p2 += __shfl_xor(p2, off, 64);
        }
        if (s == 0) {
            int gr = row0 + row;
            outf[gr * 3 + 0] = p0 + b2[0];
            outf[gr * 3 + 1] = p1 + b2[1];
            outf[gr * 3 + 2] = p2 + b2[2];
        }
    }
}

// ---------------------------------------------------------------------------
// MFMA RBF attention with shared-d2 LDS tile.
// Grid (N/32, B), 512 threads = 8 waves; wave w: head h=w&3, m-half mh=w>>2.
// Per 64-j tile: all 512 threads build d2s[32 i][64 j] (fp32, XOR-swizzled
// 16B granules) once; each wave reads its 8 d2 per kk, does mul+exp2 per
// head, packs bf16, MFMAs against swizzled V tile (double-buffered).
// LDS 76KB -> 2 blocks/CU.
// ---------------------------------------------------------------------------
__global__ __launch_bounds__(512) void attn_mfma(const float* __restrict__ xc,
                                                 const ushort* __restrict__ Vt,
                                                 ushort* __restrict__ attb) {
    __shared__ __align__(16) char Vs[2][32768];    // 64 KB
    __shared__ __align__(16) float4 cjv[2][64];    // 2 KB  (x,y,z,r2)
    __shared__ __align__(16) float4 siv[32];       // 512 B
    __shared__ __align__(16) char d2raw[8192];     // [32 i][64 j] fp32 swizzled

    int t = threadIdx.x;
    int l = t & 63, w = t >> 6;
    int h = w & 3, mh = w >> 2;
    int g = l >> 4, lr = l & 15;
    int b = blockIdx.y;
    int i_base = blockIdx.x * 32;
    const float* xb = xc + (size_t)b * N_ * 3;

    float inv = (h == 0) ? 4.f : (h == 1) ? 1.f : (h == 2) ? 0.25f : 0.0625f;
    float ch = -inv * 1.44269504088896f;   // exp(-d2*inv) = exp2(d2*ch)

    const ushort* VtB = Vt + (size_t)b * 256 * 2048;
    const ushort* vsrc[4];
    {
        int s = t & 7;
#pragma unroll
        for (int q = 0; q < 4; ++q) {
            int cc = q * 64 + (t >> 3);
            vsrc[q] = VtB + (size_t)cc * 2048 + ((s ^ (cc & 7)) << 3);
        }
    }
    auto STAGEV = [&](int buf, int jt) {
#pragma unroll
        for (int q = 0; q < 4; ++q)
            GLOAD_LDS16(vsrc[q] + jt, &Vs[buf][q * 8192 + t * 16]);
    };

    f32x4 acc[4] = {};
    f32x4 accd = {};
    short8 ones = {0x3F80, 0x3F80, 0x3F80, 0x3F80, 0x3F80, 0x3F80, 0x3F80, 0x3F80};

    // prologue: siv, cjv[0], Vs[0]
    STAGEV(0, 0);
    if (t < 32) {
        const float* p = &xb[(i_base + t) * 3];
        float x = p[0], y = p[1], z = p[2];
        siv[t] = make_float4(x, y, z, x * x + y * y + z * z);
    }
    if (t < 64) {
        const float* p = &xb[t * 3];
        float x = p[0], y = p[1], z = p[2];
        cjv[0][t] = make_float4(x, y, z, x * x + y * y + z * z);
    }
    __syncthreads();

    int bi = t & 31, jg = t >> 5;          // build mapping: row, j-granule
    int bsw = ((bi & 7) << 4);
    int rowoff = (mh * 16 + lr) * 256;
    int gsw = (lr & 7) << 4;

    for (int tt = 0; tt < N_ / 64; ++tt) {
        int cur = tt & 1;
        float nx = 0.f, ny = 0.f, nz = 0.f;
        if (tt + 1 < N_ / 64) {
            STAGEV(cur ^ 1, (tt + 1) * 64);
            if (t < 64) {
                const float* p = &xb[((tt + 1) * 64 + t) * 3];
                nx = p[0]; ny = p[1]; nz = p[2];
            }
        }
        // build shared d2 tile
        {
            float4 sv = siv[bi];
            float4 dv;
#pragma unroll
            for (int jj = 0; jj < 4; ++jj) {
                float4 cv = cjv[cur][jg * 4 + jj];
                float d = sv.w + cv.w -
                          2.f * (sv.x * cv.x + sv.y * cv.y + sv.z * cv.z);
                ((float*)&dv)[jj] = d;
            }
            *(float4*)(d2raw + bi * 256 + ((jg << 4) ^ bsw)) = dv;
        }
        if (tt + 1 < N_ / 64 && t < 64)
            cjv[cur ^ 1][t] = make_float4(nx, ny, nz, nx * nx + ny * ny + nz * nz);
        __syncthreads();   // d2s ready; Vs[cur^1] stage drained here too

        const char* buf = Vs[cur];
#pragma unroll
        for (int kk = 0; kk < 2; ++kk) {
            float4 da = *(const float4*)(d2raw + rowoff + ((kk * 128 + g * 32) ^ gsw));
            float4 db = *(const float4*)(d2raw + rowoff + ((kk * 128 + g * 32 + 16) ^ gsw));
            float ex[8];
            ex[0] = exp2f(da.x * ch); ex[1] = exp2f(da.y * ch);
            ex[2] = exp2f(da.z * ch); ex[3] = exp2f(da.w * ch);
            ex[4] = exp2f(db.x * ch); ex[5] = exp2f(db.y * ch);
            ex[6] = exp2f(db.z * ch); ex[7] = exp2f(db.w * ch);
            union { unsigned u[4]; short8 s8; } pk;
#pragma unroll
            for (int p = 0; p < 4; ++p)
                asm("v_cvt_pk_bf16_f32 %0, %1, %2"
                    : "=v"(pk.u[p]) : "v"(ex[2 * p]), "v"(ex[2 * p + 1]));
            short8 af = pk.s8;
            accd = __builtin_amdgcn_mfma_f32_16x16x32_bf16(af, ones, accd, 0, 0, 0);
            int jb = kk * 4 + g;
#pragma unroll
            for (int nn = 0; nn < 4; ++nn) {
                int c = h * 64 + nn * 16 + lr;
                short8 bf = *(const short8*)(buf + c * 128 + ((jb ^ (c & 7)) << 4));
                acc[nn] = __builtin_amdgcn_mfma_f32_16x16x32_bf16(af, bf, acc[nn], 0, 0, 0);
            }
        }
        __syncthreads();   // compute done before next build/stage overwrites
    }

#pragma unroll
    for (int r = 0; r < 4; ++r) {
        float invd = 1.f / (accd[r] + 1e-8f);
        int row = i_base + mh * 16 + g * 4 + r;
        size_t base = ((size_t)(b * N_ + row)) * 256 + h * 64 + lr;
#pragma unroll
        for (int nn = 0; nn < 4; ++nn)
            attb[base + nn * 16] = f2bf(acc[nn][r] * invd);
    }
}

// ---------------------------------------------------------------------------
extern "C" void kernel_launch(void* const* d_in, const int* in_sizes, int n_in,
                              void* d_out, int out_size, void* d_ws, size_t ws_size,
                              hipStream_t stream) {
    const float* lat    = (const float*)d_in[0];
    const float* xc     = (const float*)d_in[1];
    const float* emb    = (const float*)d_in[2];
    const float* in_W   = (const float*)d_in[3];
    const float* in_b   = (const float*)d_in[4];
    const float* val_W  = (const float*)d_in[5];
    const float* val_b  = (const float*)d_in[6];
    const float* attn_W = (const float*)d_in[7];
    const float* attn_b = (const float*)d_in[8];
    const float* ln1_g  = (const float*)d_in[9];
    const float* ln1_b  = (const float*)d_in[10];
    const float* ln2_g  = (const float*)d_in[11];
    const float* ln2_b  = (const float*)d_in[12];
    const float* ffn_W1 = (const float*)d_in[13];
    const float* ffn_b1 = (const float*)d_in[14];
    const float* ffn_W2 = (const float*)d_in[15];
    const float* ffn_b2 = (const float*)d_in[16];
    const float* out_W1 = (const float*)d_in[17];
    const float* out_b1 = (const float*)d_in[18];
    const float* out_W2 = (const float*)d_in[19];
    const float* out_b2 = (const float*)d_in[20];

    char* W = (char*)d_ws;
    float*  feats  = (float*)W;                                // 8 MB
    ushort* featsb = (ushort*)(W + (8u << 20));                // 4 MB
    ushort* attb   = (ushort*)(W + (12u << 20));               // 4 MB
    ushort* hid    = (ushort*)(W + (16u << 20));               // 8 MB
    ushort* Vt     = (ushort*)(W + (24u << 20));               // 4 MB
    ushort* wp     = (ushort*)(W + (28u << 20));               // 3.2 MB
    ushort* Wvt  = wp;
    ushort* Wat  = wp + 262144;
    ushort* W1t  = wp + 524288;
    ushort* W2t  = wp + 1048576;
    ushort* Wo1t = wp + 1572864;

    pack_weights<<<6400, 256, 0, stream>>>(val_W, attn_W, ffn_W1, ffn_W2, out_W1, wp);
    input_mlp<<<R_ / 8, 256, 0, stream>>>(xc, emb, lat, in_W, in_b, feats, featsb);

    for (int l = 0; l < LAYERS_; ++l) {
        gemmM<256, 256, 3><<<dim3(R_ / 16, 1), 256, 0, stream>>>(
            featsb, Wvt + l * 65536, val_b + l * 256,
            nullptr, nullptr, nullptr, Vt, nullptr);
        attn_mfma<<<dim3(N_ / 32, B_), 512, 0, stream>>>(xc, Vt, attb);
        gemmM<256, 256, 2><<<dim3(R_ / 16, 1), 256, 0, stream>>>(
            attb, Wat + l * 65536, attn_b + l * 256,
            feats, ln1_g + l * 256, ln1_b + l * 256, featsb, feats);
        gemmM<256, 512, 1><<<dim3(R_ / 16, 2), 256, 0, stream>>>(
            featsb, W1t + l * 131072, ffn_b1 + l * 512,
            nullptr, nullptr, nullptr, hid, nullptr);
        gemmM<512, 256, 2><<<dim3(R_ / 16, 1), 256, 0, stream>>>(
            hid, W2t + l * 131072, ffn_b2 + l * 256,
            feats, ln2_g + l * 256, ln2_b + l * 256, featsb, feats);
    }

    gemmM<256, 256, 4><<<dim3(R_ / 16, 1), 256, 0, stream>>>(
        featsb, Wo1t, out_b1, out_W2, out_b2, nullptr, nullptr, (float*)d_out);
}

// Round 5
// 331.882 us; speedup vs baseline: 1.0910x; 1.0910x over previous
//
#include <hip/hip_runtime.h>

#define B_ 4
#define N_ 2048
#define R_ (B_ * N_)      // 8192 rows
#define HID_ 256
#define EMB_ 64
#define IN_DIM_ 70
#define H_ 4
#define HEAD_ 64
#define FFN_ 512
#define LAYERS_ 4

typedef __attribute__((ext_vector_type(8))) short short8;
typedef __attribute__((ext_vector_type(4))) float f32x4;
typedef unsigned short ushort;

static __device__ __forceinline__ ushort f2bf(float f) {
    unsigned u = __builtin_bit_cast(unsigned, f);
    u += 0x7fffu + ((u >> 16) & 1u);   // RNE
    return (ushort)(u >> 16);
}
static __device__ __forceinline__ float bf2f(ushort u) {
    unsigned x = ((unsigned)u) << 16;
    return __builtin_bit_cast(float, x);
}

#define GLOAD_LDS16(g, l)                                              \
    __builtin_amdgcn_global_load_lds(                                  \
        (const __attribute__((address_space(1))) void*)(g),            \
        (__attribute__((address_space(3))) void*)(l), 16, 0, 0)

// ---------------------------------------------------------------------------
// Pack all weights to bf16, transposed [c][k] layout, in one kernel.
// Segments: Wvt 262144 | Wat 262144 | W1t 524288 | W2t 524288 | Wo1t 65536
// ---------------------------------------------------------------------------
__global__ __launch_bounds__(256) void pack_weights(const float* __restrict__ valW,
                                                    const float* __restrict__ attnW,
                                                    const float* __restrict__ ffnW1,
                                                    const float* __restrict__ ffnW2,
                                                    const float* __restrict__ outW1,
                                                    ushort* __restrict__ wp) {
    int idx = blockIdx.x * 256 + threadIdx.x;
    float v;
    if (idx < 262144) {
        int l = idx >> 16, c = (idx >> 8) & 255, k = idx & 255;
        v = valW[((l * 4 + (c >> 6)) * 256 + k) * 64 + (c & 63)];
    } else if (idx < 524288) {
        int i2 = idx - 262144;
        int l = i2 >> 16, c = (i2 >> 8) & 255, k = i2 & 255;
        v = attnW[l * 65536 + k * 256 + c];
    } else if (idx < 1048576) {
        int i2 = idx - 524288;
        int l = i2 >> 17, c = (i2 >> 8) & 511, k = i2 & 255;
        v = ffnW1[l * 131072 + k * 512 + c];
    } else if (idx < 1572864) {
        int i2 = idx - 1048576;
        int l = i2 >> 17, c = (i2 >> 9) & 255, k = i2 & 511;
        v = ffnW2[l * 131072 + k * 256 + c];
    } else {
        int i2 = idx - 1572864;
        int c = i2 >> 8, k = i2 & 255;
        v = outW1[k * 256 + c];
    }
    wp[idx] = f2bf(v);
}

// ---------------------------------------------------------------------------
// Input MLP: feats = relu(concat @ in_W + in_b); dual write fp32 + bf16
// ---------------------------------------------------------------------------
__global__ __launch_bounds__(256) void input_mlp(const float* __restrict__ xc,
                                                 const float* __restrict__ emb,
                                                 const float* __restrict__ lat,
                                                 const float* __restrict__ W,
                                                 const float* __restrict__ b,
                                                 float* __restrict__ feats,
                                                 ushort* __restrict__ featsb) {
    __shared__ float xr[8][IN_DIM_ + 2];
    int t = threadIdx.x;
    int row0 = blockIdx.x * 8;
    for (int idx = t; idx < 8 * IN_DIM_; idx += 256) {
        int r = idx / IN_DIM_, f = idx % IN_DIM_;
        int rr = row0 + r;
        float v;
        if (f < 3)       v = xc[rr * 3 + f];
        else if (f < 67) v = emb[rr * EMB_ + (f - 3)];
        else             v = lat[rr * 3 + (f - 67)];
        xr[r][f] = v;
    }
    __syncthreads();
    float acc[8] = {0.f, 0.f, 0.f, 0.f, 0.f, 0.f, 0.f, 0.f};
    for (int f = 0; f < IN_DIM_; ++f) {
        float w = W[f * HID_ + t];
#pragma unroll
        for (int r = 0; r < 8; ++r) acc[r] += xr[r][f] * w;
    }
    float bb = b[t];
#pragma unroll
    for (int r = 0; r < 8; ++r) {
        float v = fmaxf(acc[r] + bb, 0.f);
        feats[(row0 + r) * HID_ + t] = v;
        featsb[(row0 + r) * HID_ + t] = f2bf(v);
    }
}

// ---------------------------------------------------------------------------
// MFMA bf16 GEMM, double-buffered K-loop. Block = 16 rows x 256 cols,
// 256 threads = 4 waves. Wave w: cols w*64.. (N_rep=4).
// MODE 1: +bias, relu -> bf16 out            (FFN1; COLS may be 512)
// MODE 2: +bias,+resid,LN -> fp32 + bf16 out (attn-proj, FFN2)
// MODE 3: +bias -> transposed bf16 Vt[c][n]  (V-proj)
// MODE 4: +bias, relu, then @W2+b2 -> fp32 d_out (final, fused out-proj)
// ---------------------------------------------------------------------------
template <int KD, int COLS, int MODE>
__global__ __launch_bounds__(256) void gemmM(const ushort* __restrict__ A,
                                             const ushort* __restrict__ Bt,
                                             const float* __restrict__ bias,
                                             const float* __restrict__ resid,
                                             const float* __restrict__ lng,
                                             const float* __restrict__ lnb,
                                             ushort* __restrict__ outb,
                                             float* __restrict__ outf) {
    __shared__ __align__(16) char lds[69632];   // As[2]:4KB | Ws[2]:64KB
    int t = threadIdx.x;
    int l = t & 63, w = t >> 6;
    int lr = l & 15, g = l >> 4;
    int row0 = blockIdx.x * 16;
    int cbase = blockIdx.y * 256;
    f32x4 acc[4] = {};

    const ushort* srcA = A + (size_t)(row0 + (t >> 3)) * KD + (((t & 7) ^ ((t >> 3) & 7)) << 3);
    const ushort* srcB[8];
#pragma unroll
    for (int q = 0; q < 8; ++q) {
        int cl = q * 32 + (t >> 3);
        srcB[q] = Bt + (size_t)(cbase + cl) * KD + (((t & 7) ^ (cl & 7)) << 3);
    }

    auto STAGE = [&](int buf) {
        if (t < 128) GLOAD_LDS16(srcA, lds + buf * 2048 + t * 16);
#pragma unroll
        for (int q = 0; q < 8; ++q)
            GLOAD_LDS16(srcB[q], lds + 4096 + buf * 32768 + q * 4096 + t * 16);
        srcA += 64;
#pragma unroll
        for (int q = 0; q < 8; ++q) srcB[q] += 64;
    };

    int sw_a = (lr & 7) << 4;
    int aoff = lr * 128;
    constexpr int CH = KD / 64;

    STAGE(0);
#pragma unroll
    for (int c = 0; c < CH; ++c) {
        __syncthreads();            // drains STAGE(c); prev compute done
        if (c + 1 < CH) STAGE((c + 1) & 1);
        const char* As = lds + (c & 1) * 2048;
        const char* Ws = lds + 4096 + (c & 1) * 32768;

        short8 a0 = *(const short8*)(As + aoff + ((g * 16) ^ sw_a));
        short8 a1 = *(const short8*)(As + aoff + ((64 + g * 16) ^ sw_a));
#pragma unroll
        for (int n = 0; n < 4; ++n) {
            int cc = w * 64 + n * 16 + lr;
            const char* cb = Ws + cc * 128;
            int sw = (cc & 7) << 4;
            short8 b0 = *(const short8*)(cb + ((g * 16) ^ sw));
            short8 b1 = *(const short8*)(cb + ((64 + g * 16) ^ sw));
            acc[n] = __builtin_amdgcn_mfma_f32_16x16x32_bf16(a0, b0, acc[n], 0, 0, 0);
            acc[n] = __builtin_amdgcn_mfma_f32_16x16x32_bf16(a1, b1, acc[n], 0, 0, 0);
        }
    }
    __syncthreads();   // before LDS reuse in epilogues

    if constexpr (MODE == 1) {
#pragma unroll
        for (int n = 0; n < 4; ++n) {
            int c = w * 64 + n * 16 + lr;
            float bi = bias[cbase + c];
#pragma unroll
            for (int r = 0; r < 4; ++r) {
                int row = row0 + g * 4 + r;
                outb[(size_t)row * COLS + cbase + c] = f2bf(fmaxf(acc[n][r] + bi, 0.f));
            }
        }
    } else if constexpr (MODE == 2) {
        float* red1 = (float*)lds;          // [16][4]
        float* red2 = (float*)(lds + 512);
        float vals[4][4];
        float s1[4] = {0.f, 0.f, 0.f, 0.f}, s2[4] = {0.f, 0.f, 0.f, 0.f};
#pragma unroll
        for (int n = 0; n < 4; ++n) {
            int c = w * 64 + n * 16 + lr;
            float bi = bias[c];
#pragma unroll
            for (int r = 0; r < 4; ++r) {
                int row = row0 + g * 4 + r;
                float v = acc[n][r] + bi + resid[(size_t)row * 256 + c];
                vals[n][r] = v;
                s1[r] += v;
                s2[r] += v * v;
            }
        }
#pragma unroll
        for (int off = 1; off < 16; off <<= 1) {
#pragma unroll
            for (int r = 0; r < 4; ++r) {
                s1[r] += __shfl_xor(s1[r], off, 64);
                s2[r] += __shfl_xor(s2[r], off, 64);
            }
        }
        if (lr == 0) {
#pragma unroll
            for (int r = 0; r < 4; ++r) {
                red1[(g * 4 + r) * 4 + w] = s1[r];
                red2[(g * 4 + r) * 4 + w] = s2[r];
            }
        }
        __syncthreads();
        float mu[4], rstd[4];
#pragma unroll
        for (int r = 0; r < 4; ++r) {
            int rr = g * 4 + r;
            float m1 = red1[rr * 4] + red1[rr * 4 + 1] + red1[rr * 4 + 2] + red1[rr * 4 + 3];
            float m2 = red2[rr * 4] + red2[rr * 4 + 1] + red2[rr * 4 + 2] + red2[rr * 4 + 3];
            mu[r] = m1 * (1.f / 256.f);
            float var = m2 * (1.f / 256.f) - mu[r] * mu[r];
            rstd[r] = rsqrtf(var + 1e-5f);
        }
#pragma unroll
        for (int n = 0; n < 4; ++n) {
            int c = w * 64 + n * 16 + lr;
            float gg = lng[c], bb = lnb[c];
#pragma unroll
            for (int r = 0; r < 4; ++r) {
                int row = row0 + g * 4 + r;
                float o = (vals[n][r] - mu[r]) * rstd[r] * gg + bb;
                outf[(size_t)row * 256 + c] = o;
                outb[(size_t)row * 256 + c] = f2bf(o);
            }
        }
    } else if constexpr (MODE == 3) {
        ushort(*Ts)[24] = (ushort(*)[24])lds;   // [256][24]
#pragma unroll
        for (int n = 0; n < 4; ++n) {
            int c = w * 64 + n * 16 + lr;
            float bi = bias[c];
#pragma unroll
            for (int r = 0; r < 4; ++r)
                Ts[c][g * 4 + r] = f2bf(acc[n][r] + bi);
        }
        __syncthreads();
        {
            int c = t;
            int b = row0 >> 11;
            int n0 = row0 & 2047;
            ushort* dst = outb + ((size_t)(b * 256 + c)) * 2048 + n0;
            uint4 v0 = *(uint4*)&Ts[c][0];
            uint4 v1 = *(uint4*)&Ts[c][8];
            *(uint4*)dst = v0;
            *(uint4*)(dst + 8) = v1;
        }
    } else {  // MODE 4
        const float* W2 = resid;    // [256][3]
        const float* b2 = lng;      // [3]
        ushort(*Ts)[264] = (ushort(*)[264])lds;  // [16][264]
#pragma unroll
        for (int n = 0; n < 4; ++n) {
            int c = w * 64 + n * 16 + lr;
            float bi = bias[c];
#pragma unroll
            for (int r = 0; r < 4; ++r)
                Ts[g * 4 + r][c] = f2bf(fmaxf(acc[n][r] + bi, 0.f));
        }
        __syncthreads();
        int row = t >> 4, s = t & 15;
        float p0 = 0.f, p1 = 0.f, p2 = 0.f;
#pragma unroll
        for (int e = 0; e < 16; ++e) {
            float x = bf2f(Ts[row][s * 16 + e]);
            const float* wr = &W2[(s * 16 + e) * 3];
            p0 += x * wr[0];
            p1 += x * wr[1];
            p2 += x * wr[2];
        }
#pragma unroll
        for (int off = 1; off < 16; off <<= 1) {
            p0 += __shfl_xor(p0, off, 64);
            p1 += __shfl_xor(p1, off, 64);
            p2 += __shfl_xor(p2, off, 64);
        }
        if (s == 0) {
            int gr = row0 + row;
            outf[gr * 3 + 0] = p0 + b2[0];
            outf[gr * 3 + 1] = p1 + b2[1];
            outf[gr * 3 + 2] = p2 + b2[2];
        }
    }
}

// ---------------------------------------------------------------------------
// MFMA RBF attention, split by head-pair (z&1) and j-half (z>>1).
// Grid (N/32, B, 4), 256 threads = 4 waves; wave w: head hh=w&1, mh=w>>1.
// Per-wave d2 in registers (A-fragment layout), dbuf V (128 cols x 64 j)
// + dbuf coords; 1 barrier per tile. Writes bf16 partial O + fp32 partial
// denominators; attn_combine normalizes.
// ---------------------------------------------------------------------------
__global__ __launch_bounds__(256) void attn_mfma(const float* __restrict__ xc,
                                                 const ushort* __restrict__ Vt,
                                                 ushort* __restrict__ opart,
                                                 float* __restrict__ dpart) {
    __shared__ __align__(16) char Vs[2][16384];
    __shared__ __align__(16) float4 cjv[2][64];

    int t = threadIdx.x;
    int l = t & 63, w = t >> 6;
    int hh = w & 1, mh = w >> 1;
    int g = l >> 4, lr = l & 15;
    int b = blockIdx.y;
    int hp = blockIdx.z & 1, sj = blockIdx.z >> 1;
    int i_base = blockIdx.x * 32;
    int hc = hp * 128;
    int j0 = sj * (N_ / 2);
    const float* xb = xc + (size_t)b * N_ * 3;

    int h = hp * 2 + hh;
    float inv = (h == 0) ? 4.f : (h == 1) ? 1.f : (h == 2) ? 0.25f : 0.0625f;
    float ch = -inv * 1.44269504088896f;   // exp(-d2*inv) = exp2(d2*ch)

    int my_row = i_base + mh * 16 + lr;
    const float* cip = &xb[my_row * 3];
    float cix = cip[0], ciy = cip[1], ciz = cip[2];
    float ri2 = cix * cix + ciy * ciy + ciz * ciz;

    const ushort* VtB = Vt + ((size_t)b * 256 + hc) * 2048 + j0;
    const ushort* vsrc[4];
    {
        int s = t & 7;
#pragma unroll
        for (int q = 0; q < 4; ++q) {
            int cl = q * 32 + (t >> 3);
            vsrc[q] = VtB + (size_t)cl * 2048 + ((s ^ (cl & 7)) << 3);
        }
    }
    auto STAGEV = [&](int buf, int jt) {
#pragma unroll
        for (int q = 0; q < 4; ++q)
            GLOAD_LDS16(vsrc[q] + jt, &Vs[buf][q * 4096 + t * 16]);
    };

    f32x4 acc[4] = {};
    f32x4 accd = {};
    short8 ones = {0x3F80, 0x3F80, 0x3F80, 0x3F80, 0x3F80, 0x3F80, 0x3F80, 0x3F80};

    STAGEV(0, 0);
    if (t < 64) {
        const float* p = &xb[(j0 + t) * 3];
        float x = p[0], y = p[1], z = p[2];
        cjv[0][t] = make_float4(x, y, z, x * x + y * y + z * z);
    }

    constexpr int NT = (N_ / 2) / 64;   // 16 tiles
    for (int tt = 0; tt < NT; ++tt) {
        int cur = tt & 1;
        __syncthreads();   // Vs[cur]+cjv[cur] ready (vmcnt/lgkm drained); prev compute done
        if (tt + 1 < NT) {
            STAGEV(cur ^ 1, (tt + 1) * 64);
            if (t < 64) {
                const float* p = &xb[(j0 + (tt + 1) * 64 + t) * 3];
                float x = p[0], y = p[1], z = p[2];
                cjv[cur ^ 1][t] = make_float4(x, y, z, x * x + y * y + z * z);
            }
        }
        const char* buf = Vs[cur];
#pragma unroll
        for (int kk = 0; kk < 2; ++kk) {
            float ex[8];
#pragma unroll
            for (int e = 0; e < 8; ++e) {
                float4 cv = cjv[cur][kk * 32 + g * 8 + e];
                float s = cix * cv.x;
                s = fmaf(ciy, cv.y, s);
                s = fmaf(ciz, cv.z, s);
                float d2 = (ri2 + cv.w) - 2.f * s;
                ex[e] = exp2f(d2 * ch);
            }
            union { unsigned u[4]; short8 s8; } pk;
#pragma unroll
            for (int p = 0; p < 4; ++p)
                asm("v_cvt_pk_bf16_f32 %0, %1, %2"
                    : "=v"(pk.u[p]) : "v"(ex[2 * p]), "v"(ex[2 * p + 1]));
            short8 af = pk.s8;
            accd = __builtin_amdgcn_mfma_f32_16x16x32_bf16(af, ones, accd, 0, 0, 0);
            int jb = kk * 4 + g;
#pragma unroll
            for (int nn = 0; nn < 4; ++nn) {
                int c = hh * 64 + nn * 16 + lr;
                short8 bf = *(const short8*)(buf + c * 128 + ((jb ^ (c & 7)) << 4));
                acc[nn] = __builtin_amdgcn_mfma_f32_16x16x32_bf16(af, bf, acc[nn], 0, 0, 0);
            }
        }
    }

    size_t obase = ((size_t)sj * R_ + (size_t)b * N_) * 256;
#pragma unroll
    for (int r = 0; r < 4; ++r) {
        int row = i_base + mh * 16 + g * 4 + r;
        size_t rb = obase + (size_t)row * 256 + hc + hh * 64 + lr;
#pragma unroll
        for (int nn = 0; nn < 4; ++nn)
            opart[rb + nn * 16] = f2bf(acc[nn][r]);
        if (lr == 0)
            dpart[(sj * R_ + b * N_ + row) * 4 + h] = accd[r];
    }
}

// ---------------------------------------------------------------------------
// Combine j-split partials: attb = (O0+O1) / (d0+d1+1e-8), bf16.
// Grid R_/4, 256 thr; 8B per lane.
// ---------------------------------------------------------------------------
__global__ __launch_bounds__(256) void attn_combine(const ushort* __restrict__ op,
                                                    const float* __restrict__ dp,
                                                    ushort* __restrict__ attb) {
    int t = threadIdx.x;
    int row = blockIdx.x * 4 + (t >> 6);
    int c0 = (t & 63) * 4;
    uint2 a0 = *(const uint2*)(op + (size_t)row * 256 + c0);
    uint2 a1 = *(const uint2*)(op + ((size_t)R_ + row) * 256 + c0);
    int hq = c0 >> 6;
    float d = dp[row * 4 + hq] + dp[(R_ + row) * 4 + hq];
    float invd = 1.f / (d + 1e-8f);
    const ushort* p0 = (const ushort*)&a0;
    const ushort* p1 = (const ushort*)&a1;
    ushort o[4];
#pragma unroll
    for (int e = 0; e < 4; ++e)
        o[e] = f2bf((bf2f(p0[e]) + bf2f(p1[e])) * invd);
    *(uint2*)(attb + (size_t)row * 256 + c0) = *(const uint2*)o;
}

// ---------------------------------------------------------------------------
extern "C" void kernel_launch(void* const* d_in, const int* in_sizes, int n_in,
                              void* d_out, int out_size, void* d_ws, size_t ws_size,
                              hipStream_t stream) {
    const float* lat    = (const float*)d_in[0];
    const float* xc     = (const float*)d_in[1];
    const float* emb    = (const float*)d_in[2];
    const float* in_W   = (const float*)d_in[3];
    const float* in_b   = (const float*)d_in[4];
    const float* val_W  = (const float*)d_in[5];
    const float* val_b  = (const float*)d_in[6];
    const float* attn_W = (const float*)d_in[7];
    const float* attn_b = (const float*)d_in[8];
    const float* ln1_g  = (const float*)d_in[9];
    const float* ln1_b  = (const float*)d_in[10];
    const float* ln2_g  = (const float*)d_in[11];
    const float* ln2_b  = (const float*)d_in[12];
    const float* ffn_W1 = (const float*)d_in[13];
    const float* ffn_b1 = (const float*)d_in[14];
    const float* ffn_W2 = (const float*)d_in[15];
    const float* ffn_b2 = (const float*)d_in[16];
    const float* out_W1 = (const float*)d_in[17];
    const float* out_b1 = (const float*)d_in[18];
    const float* out_W2 = (const float*)d_in[19];
    const float* out_b2 = (const float*)d_in[20];

    char* W = (char*)d_ws;
    float*  feats  = (float*)W;                                // 8 MB
    ushort* featsb = (ushort*)(W + (8u << 20));                // 4 MB (first 256KB doubles as dpart during attn)
    ushort* attb   = (ushort*)(W + (12u << 20));               // 4 MB
    ushort* hid    = (ushort*)(W + (16u << 20));               // 8 MB (doubles as opart[2][R][256] during attn)
    ushort* Vt     = (ushort*)(W + (24u << 20));               // 4 MB
    ushort* wp     = (ushort*)(W + (28u << 20));               // 3.2 MB
    ushort* Wvt  = wp;
    ushort* Wat  = wp + 262144;
    ushort* W1t  = wp + 524288;
    ushort* W2t  = wp + 1048576;
    ushort* Wo1t = wp + 1572864;

    pack_weights<<<6400, 256, 0, stream>>>(val_W, attn_W, ffn_W1, ffn_W2, out_W1, wp);
    input_mlp<<<R_ / 8, 256, 0, stream>>>(xc, emb, lat, in_W, in_b, feats, featsb);

    for (int l = 0; l < LAYERS_; ++l) {
        gemmM<256, 256, 3><<<dim3(R_ / 16, 1), 256, 0, stream>>>(
            featsb, Wvt + l * 65536, val_b + l * 256,
            nullptr, nullptr, nullptr, Vt, nullptr);
        attn_mfma<<<dim3(N_ / 32, B_, 4), 256, 0, stream>>>(
            xc, Vt, hid, (float*)featsb);
        attn_combine<<<R_ / 4, 256, 0, stream>>>(hid, (float*)featsb, attb);
        gemmM<256, 256, 2><<<dim3(R_ / 16, 1), 256, 0, stream>>>(
            attb, Wat + l * 65536, attn_b + l * 256,
            feats, ln1_g + l * 256, ln1_b + l * 256, featsb, feats);
        gemmM<256, 512, 1><<<dim3(R_ / 16, 2), 256, 0, stream>>>(
            featsb, W1t + l * 131072, ffn_b1 + l * 512,
            nullptr, nullptr, nullptr, hid, nullptr);
        gemmM<512, 256, 2><<<dim3(R_ / 16, 1), 256, 0, stream>>>(
            hid, W2t + l * 131072, ffn_b2 + l * 256,
            feats, ln2_g + l * 256, ln2_b + l * 256, featsb, feats);
    }

    gemmM<256, 256, 4><<<dim3(R_ / 16, 1), 256, 0, stream>>>(
        featsb, Wo1t, out_b1, out_W2, out_b2, nullptr, nullptr, (float*)d_out);
}

// Round 6
// 307.784 us; speedup vs baseline: 1.1764x; 1.0783x over previous
//
#include <hip/hip_runtime.h>

#define B_ 4
#define N_ 2048
#define R_ (B_ * N_)      // 8192 rows
#define HID_ 256
#define EMB_ 64
#define IN_DIM_ 70
#define H_ 4
#define HEAD_ 64
#define FFN_ 512
#define LAYERS_ 4

typedef __attribute__((ext_vector_type(8))) short short8;
typedef __attribute__((ext_vector_type(4))) float f32x4;
typedef unsigned short ushort;

static __device__ __forceinline__ ushort f2bf(float f) {
    unsigned u = __builtin_bit_cast(unsigned, f);
    u += 0x7fffu + ((u >> 16) & 1u);   // RNE
    return (ushort)(u >> 16);
}
static __device__ __forceinline__ float bf2f(ushort u) {
    unsigned x = ((unsigned)u) << 16;
    return __builtin_bit_cast(float, x);
}

#define GLOAD_LDS16(g, l)                                              \
    __builtin_amdgcn_global_load_lds(                                  \
        (const __attribute__((address_space(1))) void*)(g),            \
        (__attribute__((address_space(3))) void*)(l), 16, 0, 0)

// ---------------------------------------------------------------------------
// Pack all weights to bf16, transposed [c][k] layout, in one kernel.
// Segments: Wvt 262144 | Wat 262144 | W1t 524288 | W2t 524288 | Wo1t 65536
// ---------------------------------------------------------------------------
__global__ __launch_bounds__(256) void pack_weights(const float* __restrict__ valW,
                                                    const float* __restrict__ attnW,
                                                    const float* __restrict__ ffnW1,
                                                    const float* __restrict__ ffnW2,
                                                    const float* __restrict__ outW1,
                                                    ushort* __restrict__ wp) {
    int idx = blockIdx.x * 256 + threadIdx.x;
    float v;
    if (idx < 262144) {
        int l = idx >> 16, c = (idx >> 8) & 255, k = idx & 255;
        v = valW[((l * 4 + (c >> 6)) * 256 + k) * 64 + (c & 63)];
    } else if (idx < 524288) {
        int i2 = idx - 262144;
        int l = i2 >> 16, c = (i2 >> 8) & 255, k = i2 & 255;
        v = attnW[l * 65536 + k * 256 + c];
    } else if (idx < 1048576) {
        int i2 = idx - 524288;
        int l = i2 >> 17, c = (i2 >> 8) & 511, k = i2 & 255;
        v = ffnW1[l * 131072 + k * 512 + c];
    } else if (idx < 1572864) {
        int i2 = idx - 1048576;
        int l = i2 >> 17, c = (i2 >> 9) & 255, k = i2 & 511;
        v = ffnW2[l * 131072 + k * 256 + c];
    } else {
        int i2 = idx - 1572864;
        int c = i2 >> 8, k = i2 & 255;
        v = outW1[k * 256 + c];
    }
    wp[idx] = f2bf(v);
}

// ---------------------------------------------------------------------------
// Input MLP: feats = relu(concat @ in_W + in_b); dual write fp32 + bf16
// ---------------------------------------------------------------------------
__global__ __launch_bounds__(256) void input_mlp(const float* __restrict__ xc,
                                                 const float* __restrict__ emb,
                                                 const float* __restrict__ lat,
                                                 const float* __restrict__ W,
                                                 const float* __restrict__ b,
                                                 float* __restrict__ feats,
                                                 ushort* __restrict__ featsb) {
    __shared__ float xr[8][IN_DIM_ + 2];
    int t = threadIdx.x;
    int row0 = blockIdx.x * 8;
    for (int idx = t; idx < 8 * IN_DIM_; idx += 256) {
        int r = idx / IN_DIM_, f = idx % IN_DIM_;
        int rr = row0 + r;
        float v;
        if (f < 3)       v = xc[rr * 3 + f];
        else if (f < 67) v = emb[rr * EMB_ + (f - 3)];
        else             v = lat[rr * 3 + (f - 67)];
        xr[r][f] = v;
    }
    __syncthreads();
    float acc[8] = {0.f, 0.f, 0.f, 0.f, 0.f, 0.f, 0.f, 0.f};
    for (int f = 0; f < IN_DIM_; ++f) {
        float w = W[f * HID_ + t];
#pragma unroll
        for (int r = 0; r < 8; ++r) acc[r] += xr[r][f] * w;
    }
    float bb = b[t];
#pragma unroll
    for (int r = 0; r < 8; ++r) {
        float v = fmaxf(acc[r] + bb, 0.f);
        feats[(row0 + r) * HID_ + t] = v;
        featsb[(row0 + r) * HID_ + t] = f2bf(v);
    }
}

// ---------------------------------------------------------------------------
// MFMA bf16 GEMM, double-buffered K-loop. Block = 16 rows x 256 cols,
// 256 threads = 4 waves. Wave w: cols w*64.. (N_rep=4).
// MODE 1: +bias, relu -> bf16 out            (FFN1; COLS may be 512)
// MODE 2: +bias,+resid,LN -> fp32 + bf16 out (attn-proj, FFN2)
// MODE 3: +bias -> transposed bf16 Vt[c][n]  (V-proj)
// MODE 4: +bias, relu, then @W2+b2 -> fp32 d_out (final, fused out-proj)
// ---------------------------------------------------------------------------
template <int KD, int COLS, int MODE>
__global__ __launch_bounds__(256) void gemmM(const ushort* __restrict__ A,
                                             const ushort* __restrict__ Bt,
                                             const float* __restrict__ bias,
                                             const float* __restrict__ resid,
                                             const float* __restrict__ lng,
                                             const float* __restrict__ lnb,
                                             ushort* __restrict__ outb,
                                             float* __restrict__ outf) {
    __shared__ __align__(16) char lds[69632];   // As[2]:4KB | Ws[2]:64KB
    int t = threadIdx.x;
    int l = t & 63, w = t >> 6;
    int lr = l & 15, g = l >> 4;
    int row0 = blockIdx.x * 16;
    int cbase = blockIdx.y * 256;
    f32x4 acc[4] = {};

    const ushort* srcA = A + (size_t)(row0 + (t >> 3)) * KD + (((t & 7) ^ ((t >> 3) & 7)) << 3);
    const ushort* srcB[8];
#pragma unroll
    for (int q = 0; q < 8; ++q) {
        int cl = q * 32 + (t >> 3);
        srcB[q] = Bt + (size_t)(cbase + cl) * KD + (((t & 7) ^ (cl & 7)) << 3);
    }

    auto STAGE = [&](int buf) {
        if (t < 128) GLOAD_LDS16(srcA, lds + buf * 2048 + t * 16);
#pragma unroll
        for (int q = 0; q < 8; ++q)
            GLOAD_LDS16(srcB[q], lds + 4096 + buf * 32768 + q * 4096 + t * 16);
        srcA += 64;
#pragma unroll
        for (int q = 0; q < 8; ++q) srcB[q] += 64;
    };

    int sw_a = (lr & 7) << 4;
    int aoff = lr * 128;
    constexpr int CH = KD / 64;

    STAGE(0);
#pragma unroll
    for (int c = 0; c < CH; ++c) {
        __syncthreads();            // drains STAGE(c); prev compute done
        if (c + 1 < CH) STAGE((c + 1) & 1);
        const char* As = lds + (c & 1) * 2048;
        const char* Ws = lds + 4096 + (c & 1) * 32768;

        short8 a0 = *(const short8*)(As + aoff + ((g * 16) ^ sw_a));
        short8 a1 = *(const short8*)(As + aoff + ((64 + g * 16) ^ sw_a));
#pragma unroll
        for (int n = 0; n < 4; ++n) {
            int cc = w * 64 + n * 16 + lr;
            const char* cb = Ws + cc * 128;
            int sw = (cc & 7) << 4;
            short8 b0 = *(const short8*)(cb + ((g * 16) ^ sw));
            short8 b1 = *(const short8*)(cb + ((64 + g * 16) ^ sw));
            acc[n] = __builtin_amdgcn_mfma_f32_16x16x32_bf16(a0, b0, acc[n], 0, 0, 0);
            acc[n] = __builtin_amdgcn_mfma_f32_16x16x32_bf16(a1, b1, acc[n], 0, 0, 0);
        }
    }
    __syncthreads();   // before LDS reuse in epilogues

    if constexpr (MODE == 1) {
#pragma unroll
        for (int n = 0; n < 4; ++n) {
            int c = w * 64 + n * 16 + lr;
            float bi = bias[cbase + c];
#pragma unroll
            for (int r = 0; r < 4; ++r) {
                int row = row0 + g * 4 + r;
                outb[(size_t)row * COLS + cbase + c] = f2bf(fmaxf(acc[n][r] + bi, 0.f));
            }
        }
    } else if constexpr (MODE == 2) {
        float* red1 = (float*)lds;          // [16][4]
        float* red2 = (float*)(lds + 512);
        float vals[4][4];
        float s1[4] = {0.f, 0.f, 0.f, 0.f}, s2[4] = {0.f, 0.f, 0.f, 0.f};
#pragma unroll
        for (int n = 0; n < 4; ++n) {
            int c = w * 64 + n * 16 + lr;
            float bi = bias[c];
#pragma unroll
            for (int r = 0; r < 4; ++r) {
                int row = row0 + g * 4 + r;
                float v = acc[n][r] + bi + resid[(size_t)row * 256 + c];
                vals[n][r] = v;
                s1[r] += v;
                s2[r] += v * v;
            }
        }
#pragma unroll
        for (int off = 1; off < 16; off <<= 1) {
#pragma unroll
            for (int r = 0; r < 4; ++r) {
                s1[r] += __shfl_xor(s1[r], off, 64);
                s2[r] += __shfl_xor(s2[r], off, 64);
            }
        }
        if (lr == 0) {
#pragma unroll
            for (int r = 0; r < 4; ++r) {
                red1[(g * 4 + r) * 4 + w] = s1[r];
                red2[(g * 4 + r) * 4 + w] = s2[r];
            }
        }
        __syncthreads();
        float mu[4], rstd[4];
#pragma unroll
        for (int r = 0; r < 4; ++r) {
            int rr = g * 4 + r;
            float m1 = red1[rr * 4] + red1[rr * 4 + 1] + red1[rr * 4 + 2] + red1[rr * 4 + 3];
            float m2 = red2[rr * 4] + red2[rr * 4 + 1] + red2[rr * 4 + 2] + red2[rr * 4 + 3];
            mu[r] = m1 * (1.f / 256.f);
            float var = m2 * (1.f / 256.f) - mu[r] * mu[r];
            rstd[r] = rsqrtf(var + 1e-5f);
        }
#pragma unroll
        for (int n = 0; n < 4; ++n) {
            int c = w * 64 + n * 16 + lr;
            float gg = lng[c], bb = lnb[c];
#pragma unroll
            for (int r = 0; r < 4; ++r) {
                int row = row0 + g * 4 + r;
                float o = (vals[n][r] - mu[r]) * rstd[r] * gg + bb;
                outf[(size_t)row * 256 + c] = o;
                outb[(size_t)row * 256 + c] = f2bf(o);
            }
        }
    } else if constexpr (MODE == 3) {
        ushort(*Ts)[24] = (ushort(*)[24])lds;   // [256][24]
#pragma unroll
        for (int n = 0; n < 4; ++n) {
            int c = w * 64 + n * 16 + lr;
            float bi = bias[c];
#pragma unroll
            for (int r = 0; r < 4; ++r)
                Ts[c][g * 4 + r] = f2bf(acc[n][r] + bi);
        }
        __syncthreads();
        {
            int c = t;
            int b = row0 >> 11;
            int n0 = row0 & 2047;
            ushort* dst = outb + ((size_t)(b * 256 + c)) * 2048 + n0;
            uint4 v0 = *(uint4*)&Ts[c][0];
            uint4 v1 = *(uint4*)&Ts[c][8];
            *(uint4*)dst = v0;
            *(uint4*)(dst + 8) = v1;
        }
    } else {  // MODE 4
        const float* W2 = resid;    // [256][3]
        const float* b2 = lng;      // [3]
        ushort(*Ts)[264] = (ushort(*)[264])lds;  // [16][264]
#pragma unroll
        for (int n = 0; n < 4; ++n) {
            int c = w * 64 + n * 16 + lr;
            float bi = bias[c];
#pragma unroll
            for (int r = 0; r < 4; ++r)
                Ts[g * 4 + r][c] = f2bf(fmaxf(acc[n][r] + bi, 0.f));
        }
        __syncthreads();
        int row = t >> 4, s = t & 15;
        float p0 = 0.f, p1 = 0.f, p2 = 0.f;
#pragma unroll
        for (int e = 0; e < 16; ++e) {
            float x = bf2f(Ts[row][s * 16 + e]);
            const float* wr = &W2[(s * 16 + e) * 3];
            p0 += x * wr[0];
            p1 += x * wr[1];
            p2 += x * wr[2];
        }
#pragma unroll
        for (int off = 1; off < 16; off <<= 1) {
            p0 += __shfl_xor(p0, off, 64);
            p1 += __shfl_xor(p1, off, 64);
            p2 += __shfl_xor(p2, off, 64);
        }
        if (s == 0) {
            int gr = row0 + row;
            outf[gr * 3 + 0] = p0 + b2[0];
            outf[gr * 3 + 1] = p1 + b2[1];
            outf[gr * 3 + 2] = p2 + b2[2];
        }
    }
}

// ---------------------------------------------------------------------------
// MFMA RBF attention, head-PAIR fused: one d2 feeds two heads' exp2.
// Grid (N/64, B, 8): z = hp | (sj<<1), sj in 0..3 (j-quarter).
// Block 256 thr = 4 waves; wave w = 16-row m-tile of the 64-row i-tile.
// Each wave computes full 128-col head-pair stripe: per kk, 8 d2 (dot-form),
// 2x8 exp2, 2x4 cvt_pk, 10 MFMA (4 per head + denom per head).
// V dbuf 2x16KB, coords dbuf; 1 barrier per 64-j tile. Partials out.
// ---------------------------------------------------------------------------
__global__ __launch_bounds__(256, 4) void attn_mfma(const float* __restrict__ xc,
                                                    const ushort* __restrict__ Vt,
                                                    ushort* __restrict__ opart,
                                                    float* __restrict__ dpart) {
    __shared__ __align__(16) char Vs[2][16384];
    __shared__ __align__(16) float4 cjv[2][64];

    int t = threadIdx.x;
    int l = t & 63, w = t >> 6;
    int g = l >> 4, lr = l & 15;
    int b = blockIdx.y;
    int hp = blockIdx.z & 1, sj = blockIdx.z >> 1;
    int i_base = blockIdx.x * 64;
    int hc = hp * 128;
    int j0 = sj * (N_ / 4);
    const float* xb = xc + (size_t)b * N_ * 3;

    int h0 = hp * 2;
    float inv0 = (h0 == 0) ? 4.f : 0.25f;
    float ch0 = -inv0 * 1.44269504088896f;          // exp(-d2*inv) = exp2(d2*ch)
    float ch1 = ch0 * 0.25f;                         // next lengthscale: inv/4

    int my_row = i_base + w * 16 + lr;
    const float* cip = &xb[my_row * 3];
    float cix = cip[0], ciy = cip[1], ciz = cip[2];
    float ri2 = cix * cix + ciy * ciy + ciz * ciz;

    const ushort* VtB = Vt + ((size_t)b * 256 + hc) * 2048 + j0;
    const ushort* vsrc[4];
    {
        int s = t & 7;
#pragma unroll
        for (int q = 0; q < 4; ++q) {
            int cl = q * 32 + (t >> 3);
            vsrc[q] = VtB + (size_t)cl * 2048 + ((s ^ (cl & 7)) << 3);
        }
    }
    auto STAGEV = [&](int buf, int jt) {
#pragma unroll
        for (int q = 0; q < 4; ++q)
            GLOAD_LDS16(vsrc[q] + jt, &Vs[buf][q * 4096 + t * 16]);
    };

    f32x4 acc0[4] = {}, acc1[4] = {};
    f32x4 accd0 = {}, accd1 = {};
    short8 ones = {0x3F80, 0x3F80, 0x3F80, 0x3F80, 0x3F80, 0x3F80, 0x3F80, 0x3F80};

    STAGEV(0, 0);
    if (t < 64) {
        const float* p = &xb[(j0 + t) * 3];
        float x = p[0], y = p[1], z = p[2];
        cjv[0][t] = make_float4(x, y, z, x * x + y * y + z * z);
    }

    constexpr int NT = (N_ / 4) / 64;   // 8 tiles
    for (int tt = 0; tt < NT; ++tt) {
        int cur = tt & 1;
        __syncthreads();   // Vs[cur]+cjv[cur] ready; prev compute done
        if (tt + 1 < NT) {
            STAGEV(cur ^ 1, (tt + 1) * 64);
            if (t < 64) {
                const float* p = &xb[(j0 + (tt + 1) * 64 + t) * 3];
                float x = p[0], y = p[1], z = p[2];
                cjv[cur ^ 1][t] = make_float4(x, y, z, x * x + y * y + z * z);
            }
        }
        const char* buf = Vs[cur];
#pragma unroll
        for (int kk = 0; kk < 2; ++kk) {
            float ex0[8], ex1[8];
#pragma unroll
            for (int e = 0; e < 8; ++e) {
                float4 cv = cjv[cur][kk * 32 + g * 8 + e];
                float s = cix * cv.x;
                s = fmaf(ciy, cv.y, s);
                s = fmaf(ciz, cv.z, s);
                float d2 = (ri2 + cv.w) - 2.f * s;
                ex0[e] = exp2f(d2 * ch0);
                ex1[e] = exp2f(d2 * ch1);
            }
            union { unsigned u[4]; short8 s8; } pk0, pk1;
#pragma unroll
            for (int p = 0; p < 4; ++p) {
                asm("v_cvt_pk_bf16_f32 %0, %1, %2"
                    : "=v"(pk0.u[p]) : "v"(ex0[2 * p]), "v"(ex0[2 * p + 1]));
                asm("v_cvt_pk_bf16_f32 %0, %1, %2"
                    : "=v"(pk1.u[p]) : "v"(ex1[2 * p]), "v"(ex1[2 * p + 1]));
            }
            short8 af0 = pk0.s8, af1 = pk1.s8;
            accd0 = __builtin_amdgcn_mfma_f32_16x16x32_bf16(af0, ones, accd0, 0, 0, 0);
            accd1 = __builtin_amdgcn_mfma_f32_16x16x32_bf16(af1, ones, accd1, 0, 0, 0);
            int jb = kk * 4 + g;
#pragma unroll
            for (int nn = 0; nn < 4; ++nn) {
                int c = nn * 16 + lr;               // head0 cols 0..63
                short8 bf0 = *(const short8*)(buf + c * 128 + ((jb ^ (c & 7)) << 4));
                acc0[nn] = __builtin_amdgcn_mfma_f32_16x16x32_bf16(af0, bf0, acc0[nn], 0, 0, 0);
                int c2 = 64 + nn * 16 + lr;         // head1 cols 64..127
                short8 bf1 = *(const short8*)(buf + c2 * 128 + ((jb ^ (c2 & 7)) << 4));
                acc1[nn] = __builtin_amdgcn_mfma_f32_16x16x32_bf16(af1, bf1, acc1[nn], 0, 0, 0);
            }
        }
    }

    size_t obase = ((size_t)sj * R_ + (size_t)b * N_) * 256;
#pragma unroll
    for (int r = 0; r < 4; ++r) {
        int row = i_base + w * 16 + g * 4 + r;
        size_t rb = obase + (size_t)row * 256 + hc + lr;
#pragma unroll
        for (int nn = 0; nn < 4; ++nn) {
            opart[rb + nn * 16] = f2bf(acc0[nn][r]);
            opart[rb + 64 + nn * 16] = f2bf(acc1[nn][r]);
        }
        if (lr == 0) {
            dpart[(sj * R_ + b * N_ + row) * 4 + h0] = accd0[r];
            dpart[(sj * R_ + b * N_ + row) * 4 + h0 + 1] = accd1[r];
        }
    }
}

// ---------------------------------------------------------------------------
// Combine 4 j-split partials: attb = (O0+O1+O2+O3) / (Sum d + 1e-8), bf16.
// Grid R_/4, 256 thr; 8B per lane per part.
// ---------------------------------------------------------------------------
__global__ __launch_bounds__(256) void attn_combine(const ushort* __restrict__ op,
                                                    const float* __restrict__ dp,
                                                    ushort* __restrict__ attb) {
    int t = threadIdx.x;
    int row = blockIdx.x * 4 + (t >> 6);
    int c0 = (t & 63) * 4;
    int hq = c0 >> 6;
    float d = 1e-8f;
    float s[4] = {0.f, 0.f, 0.f, 0.f};
#pragma unroll
    for (int p = 0; p < 4; ++p) {
        uint2 a = *(const uint2*)(op + ((size_t)p * R_ + row) * 256 + c0);
        const ushort* pa = (const ushort*)&a;
#pragma unroll
        for (int e = 0; e < 4; ++e) s[e] += bf2f(pa[e]);
        d += dp[(p * R_ + row) * 4 + hq];
    }
    float invd = 1.f / d;
    ushort o[4];
#pragma unroll
    for (int e = 0; e < 4; ++e) o[e] = f2bf(s[e] * invd);
    *(uint2*)(attb + (size_t)row * 256 + c0) = *(const uint2*)o;
}

// ---------------------------------------------------------------------------
extern "C" void kernel_launch(void* const* d_in, const int* in_sizes, int n_in,
                              void* d_out, int out_size, void* d_ws, size_t ws_size,
                              hipStream_t stream) {
    const float* lat    = (const float*)d_in[0];
    const float* xc     = (const float*)d_in[1];
    const float* emb    = (const float*)d_in[2];
    const float* in_W   = (const float*)d_in[3];
    const float* in_b   = (const float*)d_in[4];
    const float* val_W  = (const float*)d_in[5];
    const float* val_b  = (const float*)d_in[6];
    const float* attn_W = (const float*)d_in[7];
    const float* attn_b = (const float*)d_in[8];
    const float* ln1_g  = (const float*)d_in[9];
    const float* ln1_b  = (const float*)d_in[10];
    const float* ln2_g  = (const float*)d_in[11];
    const float* ln2_b  = (const float*)d_in[12];
    const float* ffn_W1 = (const float*)d_in[13];
    const float* ffn_b1 = (const float*)d_in[14];
    const float* ffn_W2 = (const float*)d_in[15];
    const float* ffn_b2 = (const float*)d_in[16];
    const float* out_W1 = (const float*)d_in[17];
    const float* out_b1 = (const float*)d_in[18];
    const float* out_W2 = (const float*)d_in[19];
    const float* out_b2 = (const float*)d_in[20];

    char* W = (char*)d_ws;
    float*  feats  = (float*)W;                                // 8 MB
    ushort* featsb = (ushort*)(W + (8u << 20));                // 4 MB
    ushort* attb   = (ushort*)(W + (12u << 20));               // 4 MB
    ushort* hid    = (ushort*)(W + (16u << 20));               // 8 MB
    ushort* Vt     = (ushort*)(W + (24u << 20));               // 4 MB
    ushort* wp     = (ushort*)(W + (28u << 20));               // 3.2 MB
    ushort* opart  = (ushort*)(W + (32u << 20));               // 16 MB [4][R][256] bf16
    float*  dpart  = (float*)(W + (48u << 20));                // 512 KB [4][R][4] f32
    ushort* Wvt  = wp;
    ushort* Wat  = wp + 262144;
    ushort* W1t  = wp + 524288;
    ushort* W2t  = wp + 1048576;
    ushort* Wo1t = wp + 1572864;

    pack_weights<<<6400, 256, 0, stream>>>(val_W, attn_W, ffn_W1, ffn_W2, out_W1, wp);
    input_mlp<<<R_ / 8, 256, 0, stream>>>(xc, emb, lat, in_W, in_b, feats, featsb);

    for (int l = 0; l < LAYERS_; ++l) {
        gemmM<256, 256, 3><<<dim3(R_ / 16, 1), 256, 0, stream>>>(
            featsb, Wvt + l * 65536, val_b + l * 256,
            nullptr, nullptr, nullptr, Vt, nullptr);
        attn_mfma<<<dim3(N_ / 64, B_, 8), 256, 0, stream>>>(
            xc, Vt, opart, dpart);
        attn_combine<<<R_ / 4, 256, 0, stream>>>(opart, dpart, attb);
        gemmM<256, 256, 2><<<dim3(R_ / 16, 1), 256, 0, stream>>>(
            attb, Wat + l * 65536, attn_b + l * 256,
            feats, ln1_g + l * 256, ln1_b + l * 256, featsb, feats);
        gemmM<256, 512, 1><<<dim3(R_ / 16, 2), 256, 0, stream>>>(
            featsb, W1t + l * 131072, ffn_b1 + l * 512,
            nullptr, nullptr, nullptr, hid, nullptr);
        gemmM<512, 256, 2><<<dim3(R_ / 16, 1), 256, 0, stream>>>(
            hid, W2t + l * 131072, ffn_b2 + l * 256,
            feats, ln2_g + l * 256, ln2_b + l * 256, featsb, feats);
    }

    gemmM<256, 256, 4><<<dim3(R_ / 16, 1), 256, 0, stream>>>(
        featsb, Wo1t, out_b1, out_W2, out_b2, nullptr, nullptr, (float*)d_out);
}

// Round 7
// 303.946 us; speedup vs baseline: 1.1913x; 1.0126x over previous
//
#include <hip/hip_runtime.h>

#define B_ 4
#define N_ 2048
#define R_ (B_ * N_)      // 8192 rows
#define HID_ 256
#define EMB_ 64
#define IN_DIM_ 70
#define H_ 4
#define HEAD_ 64
#define FFN_ 512
#define LAYERS_ 4

typedef __attribute__((ext_vector_type(8))) short short8;
typedef __attribute__((ext_vector_type(4))) float f32x4;
typedef unsigned short ushort;

static __device__ __forceinline__ ushort f2bf(float f) {
    unsigned u = __builtin_bit_cast(unsigned, f);
    u += 0x7fffu + ((u >> 16) & 1u);   // RNE
    return (ushort)(u >> 16);
}
static __device__ __forceinline__ float bf2f(ushort u) {
    unsigned x = ((unsigned)u) << 16;
    return __builtin_bit_cast(float, x);
}

#define GLOAD_LDS16(g, l)                                              \
    __builtin_amdgcn_global_load_lds(                                  \
        (const __attribute__((address_space(1))) void*)(g),            \
        (__attribute__((address_space(3))) void*)(l), 16, 0, 0)

// ---------------------------------------------------------------------------
// Pack all weights to bf16, transposed [c][k] layout, in one kernel.
// Segments: Wvt 262144 | Wat 262144 | W1t 524288 | W2t 524288 | Wo1t 65536
// ---------------------------------------------------------------------------
__global__ __launch_bounds__(256) void pack_weights(const float* __restrict__ valW,
                                                    const float* __restrict__ attnW,
                                                    const float* __restrict__ ffnW1,
                                                    const float* __restrict__ ffnW2,
                                                    const float* __restrict__ outW1,
                                                    ushort* __restrict__ wp) {
    int idx = blockIdx.x * 256 + threadIdx.x;
    float v;
    if (idx < 262144) {
        int l = idx >> 16, c = (idx >> 8) & 255, k = idx & 255;
        v = valW[((l * 4 + (c >> 6)) * 256 + k) * 64 + (c & 63)];
    } else if (idx < 524288) {
        int i2 = idx - 262144;
        int l = i2 >> 16, c = (i2 >> 8) & 255, k = i2 & 255;
        v = attnW[l * 65536 + k * 256 + c];
    } else if (idx < 1048576) {
        int i2 = idx - 524288;
        int l = i2 >> 17, c = (i2 >> 8) & 511, k = i2 & 255;
        v = ffnW1[l * 131072 + k * 512 + c];
    } else if (idx < 1572864) {
        int i2 = idx - 1048576;
        int l = i2 >> 17, c = (i2 >> 9) & 255, k = i2 & 511;
        v = ffnW2[l * 131072 + k * 256 + c];
    } else {
        int i2 = idx - 1572864;
        int c = i2 >> 8, k = i2 & 255;
        v = outW1[k * 256 + c];
    }
    wp[idx] = f2bf(v);
}

// ---------------------------------------------------------------------------
// Input MLP: feats = relu(concat @ in_W + in_b); dual write fp32 + bf16
// ---------------------------------------------------------------------------
__global__ __launch_bounds__(256) void input_mlp(const float* __restrict__ xc,
                                                 const float* __restrict__ emb,
                                                 const float* __restrict__ lat,
                                                 const float* __restrict__ W,
                                                 const float* __restrict__ b,
                                                 float* __restrict__ feats,
                                                 ushort* __restrict__ featsb) {
    __shared__ float xr[8][IN_DIM_ + 2];
    int t = threadIdx.x;
    int row0 = blockIdx.x * 8;
    for (int idx = t; idx < 8 * IN_DIM_; idx += 256) {
        int r = idx / IN_DIM_, f = idx % IN_DIM_;
        int rr = row0 + r;
        float v;
        if (f < 3)       v = xc[rr * 3 + f];
        else if (f < 67) v = emb[rr * EMB_ + (f - 3)];
        else             v = lat[rr * 3 + (f - 67)];
        xr[r][f] = v;
    }
    __syncthreads();
    float acc[8] = {0.f, 0.f, 0.f, 0.f, 0.f, 0.f, 0.f, 0.f};
    for (int f = 0; f < IN_DIM_; ++f) {
        float w = W[f * HID_ + t];
#pragma unroll
        for (int r = 0; r < 8; ++r) acc[r] += xr[r][f] * w;
    }
    float bb = b[t];
#pragma unroll
    for (int r = 0; r < 8; ++r) {
        float v = fmaxf(acc[r] + bb, 0.f);
        feats[(row0 + r) * HID_ + t] = v;
        featsb[(row0 + r) * HID_ + t] = f2bf(v);
    }
}

// ---------------------------------------------------------------------------
// MFMA bf16 GEMM, double-buffered K-loop (MODE3: V-proj, MODE4: final).
// ---------------------------------------------------------------------------
template <int KD, int COLS, int MODE>
__global__ __launch_bounds__(256) void gemmM(const ushort* __restrict__ A,
                                             const ushort* __restrict__ Bt,
                                             const float* __restrict__ bias,
                                             const float* __restrict__ resid,
                                             const float* __restrict__ lng,
                                             const float* __restrict__ lnb,
                                             ushort* __restrict__ outb,
                                             float* __restrict__ outf) {
    __shared__ __align__(16) char lds[69632];   // As[2]:4KB | Ws[2]:64KB
    int t = threadIdx.x;
    int l = t & 63, w = t >> 6;
    int lr = l & 15, g = l >> 4;
    int row0 = blockIdx.x * 16;
    int cbase = blockIdx.y * 256;
    f32x4 acc[4] = {};

    const ushort* srcA = A + (size_t)(row0 + (t >> 3)) * KD + (((t & 7) ^ ((t >> 3) & 7)) << 3);
    const ushort* srcB[8];
#pragma unroll
    for (int q = 0; q < 8; ++q) {
        int cl = q * 32 + (t >> 3);
        srcB[q] = Bt + (size_t)(cbase + cl) * KD + (((t & 7) ^ (cl & 7)) << 3);
    }

    auto STAGE = [&](int buf) {
        if (t < 128) GLOAD_LDS16(srcA, lds + buf * 2048 + t * 16);
#pragma unroll
        for (int q = 0; q < 8; ++q)
            GLOAD_LDS16(srcB[q], lds + 4096 + buf * 32768 + q * 4096 + t * 16);
        srcA += 64;
#pragma unroll
        for (int q = 0; q < 8; ++q) srcB[q] += 64;
    };

    int sw_a = (lr & 7) << 4;
    int aoff = lr * 128;
    constexpr int CH = KD / 64;

    STAGE(0);
#pragma unroll
    for (int c = 0; c < CH; ++c) {
        __syncthreads();
        if (c + 1 < CH) STAGE((c + 1) & 1);
        const char* As = lds + (c & 1) * 2048;
        const char* Ws = lds + 4096 + (c & 1) * 32768;

        short8 a0 = *(const short8*)(As + aoff + ((g * 16) ^ sw_a));
        short8 a1 = *(const short8*)(As + aoff + ((64 + g * 16) ^ sw_a));
#pragma unroll
        for (int n = 0; n < 4; ++n) {
            int cc = w * 64 + n * 16 + lr;
            const char* cb = Ws + cc * 128;
            int sw = (cc & 7) << 4;
            short8 b0 = *(const short8*)(cb + ((g * 16) ^ sw));
            short8 b1 = *(const short8*)(cb + ((64 + g * 16) ^ sw));
            acc[n] = __builtin_amdgcn_mfma_f32_16x16x32_bf16(a0, b0, acc[n], 0, 0, 0);
            acc[n] = __builtin_amdgcn_mfma_f32_16x16x32_bf16(a1, b1, acc[n], 0, 0, 0);
        }
    }
    __syncthreads();

    if constexpr (MODE == 3) {
        ushort(*Ts)[24] = (ushort(*)[24])lds;   // [256][24]
#pragma unroll
        for (int n = 0; n < 4; ++n) {
            int c = w * 64 + n * 16 + lr;
            float bi = bias[c];
#pragma unroll
            for (int r = 0; r < 4; ++r)
                Ts[c][g * 4 + r] = f2bf(acc[n][r] + bi);
        }
        __syncthreads();
        {
            int c = t;
            int b = row0 >> 11;
            int n0 = row0 & 2047;
            ushort* dst = outb + ((size_t)(b * 256 + c)) * 2048 + n0;
            uint4 v0 = *(uint4*)&Ts[c][0];
            uint4 v1 = *(uint4*)&Ts[c][8];
            *(uint4*)dst = v0;
            *(uint4*)(dst + 8) = v1;
        }
    } else {  // MODE 4
        const float* W2 = resid;    // [256][3]
        const float* b2 = lng;      // [3]
        ushort(*Ts)[264] = (ushort(*)[264])lds;  // [16][264]
#pragma unroll
        for (int n = 0; n < 4; ++n) {
            int c = w * 64 + n * 16 + lr;
            float bi = bias[c];
#pragma unroll
            for (int r = 0; r < 4; ++r)
                Ts[g * 4 + r][c] = f2bf(fmaxf(acc[n][r] + bi, 0.f));
        }
        __syncthreads();
        int row = t >> 4, s = t & 15;
        float p0 = 0.f, p1 = 0.f, p2 = 0.f;
#pragma unroll
        for (int e = 0; e < 16; ++e) {
            float x = bf2f(Ts[row][s * 16 + e]);
            const float* wr = &W2[(s * 16 + e) * 3];
            p0 += x * wr[0];
            p1 += x * wr[1];
            p2 += x * wr[2];
        }
#pragma unroll
        for (int off = 1; off < 16; off <<= 1) {
            p0 += __shfl_xor(p0, off, 64);
            p1 += __shfl_xor(p1, off, 64);
            p2 += __shfl_xor(p2, off, 64);
        }
        if (s == 0) {
            int gr = row0 + row;
            outf[gr * 3 + 0] = p0 + b2[0];
            outf[gr * 3 + 1] = p1 + b2[1];
            outf[gr * 3 + 2] = p2 + b2[2];
        }
    }
}

// ---------------------------------------------------------------------------
// gemmA: fused attn-combine + attn-proj + LN1. A = sum_p opart[p]*invd
// reg-staged (loads issued early, processed+ds_written after compute - T14).
// B dbuf via global_load_lds as gemmM. KD=256. Epilogue: bias+resid+LN.
// ---------------------------------------------------------------------------
__global__ __launch_bounds__(256) void gemmA(const ushort* __restrict__ op,
                                             const float* __restrict__ dp,
                                             const ushort* __restrict__ Bt,
                                             const float* __restrict__ bias,
                                             const float* __restrict__ resid,
                                             const float* __restrict__ lng,
                                             const float* __restrict__ lnb,
                                             ushort* __restrict__ outb,
                                             float* __restrict__ outf) {
    __shared__ __align__(16) char lds[69632];   // As[2]:4KB | Ws[2]:64KB
    int t = threadIdx.x;
    int l = t & 63, w = t >> 6;
    int lr = l & 15, g = l >> 4;
    int row0 = blockIdx.x * 16;
    f32x4 acc[4] = {};

    const ushort* srcB[8];
#pragma unroll
    for (int q = 0; q < 8; ++q) {
        int cl = q * 32 + (t >> 3);
        srcB[q] = Bt + (size_t)cl * 256 + (((t & 7) ^ (cl & 7)) << 3);
    }
    auto STAGE_B = [&](int buf) {
#pragma unroll
        for (int q = 0; q < 8; ++q)
            GLOAD_LDS16(srcB[q], lds + 4096 + buf * 32768 + q * 4096 + t * 16);
#pragma unroll
        for (int q = 0; q < 8; ++q) srcB[q] += 64;
    };

    // A reg-staging: thread t<128 owns (row=t>>3, kslot=(t&7)^(row&7))
    int arow = t >> 3;
    int kslot = (t & 7) ^ (arow & 7);
    const ushort* asrc = op + (size_t)(row0 + arow) * 256 + (kslot << 3);
    float inv4[4] = {1.f, 1.f, 1.f, 1.f};
    if (t < 128) {
        int grow = row0 + arow;
#pragma unroll
        for (int hq = 0; hq < 4; ++hq) {
            float d = 1e-8f;
#pragma unroll
            for (int p = 0; p < 4; ++p) d += dp[(p * R_ + grow) * 4 + hq];
            inv4[hq] = 1.f / d;
        }
    }
    uint4 ar0, ar1, ar2, ar3;
    auto ALOAD = [&](int c) {
        if (t < 128) {
            const ushort* s0 = asrc + c * 64;
            ar0 = *(const uint4*)s0;
            ar1 = *(const uint4*)(s0 + (size_t)R_ * 256);
            ar2 = *(const uint4*)(s0 + (size_t)2 * R_ * 256);
            ar3 = *(const uint4*)(s0 + (size_t)3 * R_ * 256);
        }
    };
    auto APROC = [&](int buf, int c) {
        if (t < 128) {
            const ushort* p0 = (const ushort*)&ar0;
            const ushort* p1 = (const ushort*)&ar1;
            const ushort* p2 = (const ushort*)&ar2;
            const ushort* p3 = (const ushort*)&ar3;
            float iv = inv4[c];
            float s[8];
#pragma unroll
            for (int e = 0; e < 8; ++e)
                s[e] = ((bf2f(p0[e]) + bf2f(p1[e])) + (bf2f(p2[e]) + bf2f(p3[e]))) * iv;
            union { unsigned u[4]; uint4 v; } pk;
#pragma unroll
            for (int q = 0; q < 4; ++q)
                asm("v_cvt_pk_bf16_f32 %0, %1, %2"
                    : "=v"(pk.u[q]) : "v"(s[2 * q]), "v"(s[2 * q + 1]));
            *(uint4*)(lds + buf * 2048 + t * 16) = pk.v;
        }
    };

    int sw_a = (lr & 7) << 4;
    int aoff = lr * 128;

    STAGE_B(0);
    ALOAD(0);
    APROC(0, 0);
#pragma unroll
    for (int c = 0; c < 4; ++c) {
        __syncthreads();
        if (c + 1 < 4) { STAGE_B((c + 1) & 1); ALOAD(c + 1); }
        const char* As = lds + (c & 1) * 2048;
        const char* Ws = lds + 4096 + (c & 1) * 32768;

        short8 a0 = *(const short8*)(As + aoff + ((g * 16) ^ sw_a));
        short8 a1 = *(const short8*)(As + aoff + ((64 + g * 16) ^ sw_a));
#pragma unroll
        for (int n = 0; n < 4; ++n) {
            int cc = w * 64 + n * 16 + lr;
            const char* cb = Ws + cc * 128;
            int sw = (cc & 7) << 4;
            short8 b0 = *(const short8*)(cb + ((g * 16) ^ sw));
            short8 b1 = *(const short8*)(cb + ((64 + g * 16) ^ sw));
            acc[n] = __builtin_amdgcn_mfma_f32_16x16x32_bf16(a0, b0, acc[n], 0, 0, 0);
            acc[n] = __builtin_amdgcn_mfma_f32_16x16x32_bf16(a1, b1, acc[n], 0, 0, 0);
        }
        if (c + 1 < 4) APROC((c + 1) & 1, c + 1);
    }
    __syncthreads();

    // LN epilogue (bias + resid + LayerNorm, dual write)
    float* red1 = (float*)lds;
    float* red2 = (float*)(lds + 512);
    float vals[4][4];
    float s1[4] = {0.f, 0.f, 0.f, 0.f}, s2[4] = {0.f, 0.f, 0.f, 0.f};
#pragma unroll
    for (int n = 0; n < 4; ++n) {
        int c = w * 64 + n * 16 + lr;
        float bi = bias[c];
#pragma unroll
        for (int r = 0; r < 4; ++r) {
            int row = row0 + g * 4 + r;
            float v = acc[n][r] + bi + resid[(size_t)row * 256 + c];
            vals[n][r] = v;
            s1[r] += v;
            s2[r] += v * v;
        }
    }
#pragma unroll
    for (int off = 1; off < 16; off <<= 1) {
#pragma unroll
        for (int r = 0; r < 4; ++r) {
            s1[r] += __shfl_xor(s1[r], off, 64);
            s2[r] += __shfl_xor(s2[r], off, 64);
        }
    }
    if (lr == 0) {
#pragma unroll
        for (int r = 0; r < 4; ++r) {
            red1[(g * 4 + r) * 4 + w] = s1[r];
            red2[(g * 4 + r) * 4 + w] = s2[r];
        }
    }
    __syncthreads();
#pragma unroll
    for (int n = 0; n < 4; ++n) {
        int c = w * 64 + n * 16 + lr;
        float gg = lng[c], bb = lnb[c];
#pragma unroll
        for (int r = 0; r < 4; ++r) {
            int rr = g * 4 + r;
            float m1 = red1[rr * 4] + red1[rr * 4 + 1] + red1[rr * 4 + 2] + red1[rr * 4 + 3];
            float m2 = red2[rr * 4] + red2[rr * 4 + 1] + red2[rr * 4 + 2] + red2[rr * 4 + 3];
            float mu = m1 * (1.f / 256.f);
            float var = m2 * (1.f / 256.f) - mu * mu;
            float rstd = rsqrtf(var + 1e-5f);
            int row = row0 + rr;
            float o = (vals[n][r] - mu) * rstd * gg + bb;
            outf[(size_t)row * 256 + c] = o;
            outb[(size_t)row * 256 + c] = f2bf(o);
        }
    }
}

// ---------------------------------------------------------------------------
// gemmF: fused FFN1 + ReLU + FFN2 + LN2. A staged once to LDS (8KB, swizzled);
// W tiles reg-double-buffered (global->reg issued under compute, ds_write at
// chunk top). hid kept in LDS (16KB, row-XOR swizzled). KD1=256, KD2=512.
// LDS: As 8KB | Ws 32KB | hid 16KB = 56KB.
// ---------------------------------------------------------------------------
__global__ __launch_bounds__(256) void gemmF(const ushort* __restrict__ A,
                                             const ushort* __restrict__ W1t,
                                             const float* __restrict__ b1,
                                             const ushort* __restrict__ W2t,
                                             const float* __restrict__ b2,
                                             const float* __restrict__ resid,
                                             const float* __restrict__ lng,
                                             const float* __restrict__ lnb,
                                             ushort* __restrict__ outb,
                                             float* __restrict__ outf) {
    __shared__ __align__(16) char lds[57344];
    char* Asp = lds;            // 8KB: [16 rows][512B], slot s holds k=(s^(row&7))*8
    char* Wsp = lds + 8192;     // 32KB
    char* hidp = lds + 40960;   // 16KB: [16 rows][1024B], byte (k*2)^((row&7)<<4)

    int t = threadIdx.x;
    int l = t & 63, w = t >> 6;
    int lr = l & 15, g = l >> 4;
    int row0 = blockIdx.x * 16;
    int sw_a = (lr & 7) << 4;

    // stage all of A (16 x 256 bf16) once
#pragma unroll
    for (int shot = 0; shot < 2; ++shot) {
        int si = shot * 256 + t;
        int row = si >> 5, sl = si & 31;
        const ushort* src = A + (size_t)(row0 + row) * 256 + ((sl ^ (row & 7)) << 3);
        GLOAD_LDS16(src, Asp + si * 16);
    }

    uint4 wr0, wr1, wr2, wr3, wr4, wr5, wr6, wr7;
    auto WLOAD1 = [&](int ch, int c) {
        const ushort* base = W1t + c * 64;
#pragma unroll
        for (int q = 0; q < 8; ++q) {
            int cl = ch * 256 + q * 32 + (t >> 3);
            const uint4* s = (const uint4*)(base + (size_t)cl * 256 + (((t & 7) ^ (cl & 7)) << 3));
            uint4 v = *s;
            if (q == 0) wr0 = v; else if (q == 1) wr1 = v; else if (q == 2) wr2 = v;
            else if (q == 3) wr3 = v; else if (q == 4) wr4 = v; else if (q == 5) wr5 = v;
            else if (q == 6) wr6 = v; else wr7 = v;
        }
    };
    auto WLOAD2 = [&](int c) {
        const ushort* base = W2t + c * 64;
#pragma unroll
        for (int q = 0; q < 8; ++q) {
            int cl = q * 32 + (t >> 3);
            const uint4* s = (const uint4*)(base + (size_t)cl * 512 + (((t & 7) ^ (cl & 7)) << 3));
            uint4 v = *s;
            if (q == 0) wr0 = v; else if (q == 1) wr1 = v; else if (q == 2) wr2 = v;
            else if (q == 3) wr3 = v; else if (q == 4) wr4 = v; else if (q == 5) wr5 = v;
            else if (q == 6) wr6 = v; else wr7 = v;
        }
    };
    auto WSTORE = [&]() {
        *(uint4*)(Wsp + 0 * 4096 + t * 16) = wr0;
        *(uint4*)(Wsp + 1 * 4096 + t * 16) = wr1;
        *(uint4*)(Wsp + 2 * 4096 + t * 16) = wr2;
        *(uint4*)(Wsp + 3 * 4096 + t * 16) = wr3;
        *(uint4*)(Wsp + 4 * 4096 + t * 16) = wr4;
        *(uint4*)(Wsp + 5 * 4096 + t * 16) = wr5;
        *(uint4*)(Wsp + 6 * 4096 + t * 16) = wr6;
        *(uint4*)(Wsp + 7 * 4096 + t * 16) = wr7;
    };

    WLOAD1(0, 0);

    // ---- phase 1: FFN1 halves ----
#pragma unroll
    for (int ch = 0; ch < 2; ++ch) {
        f32x4 acc[4] = {};
#pragma unroll
        for (int c = 0; c < 4; ++c) {
            __syncthreads();               // Ws free (prev compute / hid writes done)
            WSTORE();
            __syncthreads();               // Ws + (first iter) As visible
            // issue next W loads (hidden under compute)
            if (c < 3) WLOAD1(ch, c + 1);
            else if (ch == 0) WLOAD1(1, 0);
            else WLOAD2(0);

            short8 a0 = *(const short8*)(Asp + lr * 512 + ((c * 128 + g * 16) ^ sw_a));
            short8 a1 = *(const short8*)(Asp + lr * 512 + ((c * 128 + 64 + g * 16) ^ sw_a));
#pragma unroll
            for (int n = 0; n < 4; ++n) {
                int cc = w * 64 + n * 16 + lr;
                const char* cb = Wsp + cc * 128;
                int sw = (cc & 7) << 4;
                short8 b0 = *(const short8*)(cb + ((g * 16) ^ sw));
                short8 b1 = *(const short8*)(cb + ((64 + g * 16) ^ sw));
                acc[n] = __builtin_amdgcn_mfma_f32_16x16x32_bf16(a0, b0, acc[n], 0, 0, 0);
                acc[n] = __builtin_amdgcn_mfma_f32_16x16x32_bf16(a1, b1, acc[n], 0, 0, 0);
            }
        }
        // relu -> hid LDS (swizzled scatter)
#pragma unroll
        for (int n = 0; n < 4; ++n) {
            int c = w * 64 + n * 16 + lr;
            float bi = b1[ch * 256 + c];
#pragma unroll
            for (int r = 0; r < 4; ++r) {
                int rw = g * 4 + r;
                float v = fmaxf(acc[n][r] + bi, 0.f);
                int byte = rw * 1024 + (((ch * 256 + c) * 2) ^ ((rw & 7) << 4));
                *(ushort*)(hidp + byte) = f2bf(v);
            }
        }
    }

    // ---- phase 2: FFN2 (K=512, A from hid LDS) ----
    f32x4 acc2[4] = {};
#pragma unroll
    for (int c = 0; c < 8; ++c) {
        __syncthreads();                   // hid writes (first) / prev compute done
        WSTORE();
        __syncthreads();
        if (c < 7) WLOAD2(c + 1);

        short8 a0 = *(const short8*)(hidp + lr * 1024 + ((c * 128 + g * 16) ^ sw_a));
        short8 a1 = *(const short8*)(hidp + lr * 1024 + ((c * 128 + 64 + g * 16) ^ sw_a));
#pragma unroll
        for (int n = 0; n < 4; ++n) {
            int cc = w * 64 + n * 16 + lr;
            const char* cb = Wsp + cc * 128;
            int sw = (cc & 7) << 4;
            short8 b0 = *(const short8*)(cb + ((g * 16) ^ sw));
            short8 b1 = *(const short8*)(cb + ((64 + g * 16) ^ sw));
            acc2[n] = __builtin_amdgcn_mfma_f32_16x16x32_bf16(a0, b0, acc2[n], 0, 0, 0);
            acc2[n] = __builtin_amdgcn_mfma_f32_16x16x32_bf16(a1, b1, acc2[n], 0, 0, 0);
        }
    }
    __syncthreads();

    // LN epilogue
    float* red1 = (float*)lds;
    float* red2 = (float*)(lds + 512);
    float vals[4][4];
    float s1[4] = {0.f, 0.f, 0.f, 0.f}, s2[4] = {0.f, 0.f, 0.f, 0.f};
#pragma unroll
    for (int n = 0; n < 4; ++n) {
        int c = w * 64 + n * 16 + lr;
        float bi = b2[c];
#pragma unroll
        for (int r = 0; r < 4; ++r) {
            int row = row0 + g * 4 + r;
            float v = acc2[n][r] + bi + resid[(size_t)row * 256 + c];
            vals[n][r] = v;
            s1[r] += v;
            s2[r] += v * v;
        }
    }
#pragma unroll
    for (int off = 1; off < 16; off <<= 1) {
#pragma unroll
        for (int r = 0; r < 4; ++r) {
            s1[r] += __shfl_xor(s1[r], off, 64);
            s2[r] += __shfl_xor(s2[r], off, 64);
        }
    }
    if (lr == 0) {
#pragma unroll
        for (int r = 0; r < 4; ++r) {
            red1[(g * 4 + r) * 4 + w] = s1[r];
            red2[(g * 4 + r) * 4 + w] = s2[r];
        }
    }
    __syncthreads();
#pragma unroll
    for (int n = 0; n < 4; ++n) {
        int c = w * 64 + n * 16 + lr;
        float gg = lng[c], bb = lnb[c];
#pragma unroll
        for (int r = 0; r < 4; ++r) {
            int rr = g * 4 + r;
            float m1 = red1[rr * 4] + red1[rr * 4 + 1] + red1[rr * 4 + 2] + red1[rr * 4 + 3];
            float m2 = red2[rr * 4] + red2[rr * 4 + 1] + red2[rr * 4 + 2] + red2[rr * 4 + 3];
            float mu = m1 * (1.f / 256.f);
            float var = m2 * (1.f / 256.f) - mu * mu;
            float rstd = rsqrtf(var + 1e-5f);
            int row = row0 + rr;
            float o = (vals[n][r] - mu) * rstd * gg + bb;
            outf[(size_t)row * 256 + c] = o;
            outb[(size_t)row * 256 + c] = f2bf(o);
        }
    }
}

// ---------------------------------------------------------------------------
// MFMA RBF attention (R6 structure) + XCD-aware block decode: 1-D grid 1024;
// all 32 i-blocks of one (b, head-pair, j-quarter) combo land on one XCD so
// its 128KB Vt slice stays L2-hot.
// ---------------------------------------------------------------------------
__global__ __launch_bounds__(256, 4) void attn_mfma(const float* __restrict__ xc,
                                                    const ushort* __restrict__ Vt,
                                                    ushort* __restrict__ opart,
                                                    float* __restrict__ dpart) {
    __shared__ __align__(16) char Vs[2][16384];
    __shared__ __align__(16) float4 cjv[2][64];

    int t = threadIdx.x;
    int l = t & 63, w = t >> 6;
    int g = l >> 4, lr = l & 15;

    int f = blockIdx.x;
    int xcd = f & 7, s = f >> 3;
    int combo = xcd + 8 * (s >> 5);      // 0..31, constant per XCD-slice
    int ib = s & 31;
    int b = combo & 3;
    int z = combo >> 2;
    int hp = z & 1, sj = z >> 1;
    int i_base = ib * 64;
    int hc = hp * 128;
    int j0 = sj * (N_ / 4);
    const float* xb = xc + (size_t)b * N_ * 3;

    int h0 = hp * 2;
    float inv0 = (h0 == 0) ? 4.f : 0.25f;
    float ch0 = -inv0 * 1.44269504088896f;
    float ch1 = ch0 * 0.25f;

    int my_row = i_base + w * 16 + lr;
    const float* cip = &xb[my_row * 3];
    float cix = cip[0], ciy = cip[1], ciz = cip[2];
    float ri2 = cix * cix + ciy * ciy + ciz * ciz;

    const ushort* VtB = Vt + ((size_t)b * 256 + hc) * 2048 + j0;
    const ushort* vsrc[4];
    {
        int ss = t & 7;
#pragma unroll
        for (int q = 0; q < 4; ++q) {
            int cl = q * 32 + (t >> 3);
            vsrc[q] = VtB + (size_t)cl * 2048 + ((ss ^ (cl & 7)) << 3);
        }
    }
    auto STAGEV = [&](int buf, int jt) {
#pragma unroll
        for (int q = 0; q < 4; ++q)
            GLOAD_LDS16(vsrc[q] + jt, &Vs[buf][q * 4096 + t * 16]);
    };

    f32x4 acc0[4] = {}, acc1[4] = {};
    f32x4 accd0 = {}, accd1 = {};
    short8 ones = {0x3F80, 0x3F80, 0x3F80, 0x3F80, 0x3F80, 0x3F80, 0x3F80, 0x3F80};

    STAGEV(0, 0);
    if (t < 64) {
        const float* p = &xb[(j0 + t) * 3];
        float x = p[0], y = p[1], zz = p[2];
        cjv[0][t] = make_float4(x, y, zz, x * x + y * y + zz * zz);
    }

    constexpr int NT = (N_ / 4) / 64;   // 8 tiles
    for (int tt = 0; tt < NT; ++tt) {
        int cur = tt & 1;
        __syncthreads();
        if (tt + 1 < NT) {
            STAGEV(cur ^ 1, (tt + 1) * 64);
            if (t < 64) {
                const float* p = &xb[(j0 + (tt + 1) * 64 + t) * 3];
                float x = p[0], y = p[1], zz = p[2];
                cjv[cur ^ 1][t] = make_float4(x, y, zz, x * x + y * y + zz * zz);
            }
        }
        const char* buf = Vs[cur];
#pragma unroll
        for (int kk = 0; kk < 2; ++kk) {
            float ex0[8], ex1[8];
#pragma unroll
            for (int e = 0; e < 8; ++e) {
                float4 cv = cjv[cur][kk * 32 + g * 8 + e];
                float sd = cix * cv.x;
                sd = fmaf(ciy, cv.y, sd);
                sd = fmaf(ciz, cv.z, sd);
                float d2 = (ri2 + cv.w) - 2.f * sd;
                ex0[e] = exp2f(d2 * ch0);
                ex1[e] = exp2f(d2 * ch1);
            }
            union { unsigned u[4]; short8 s8; } pk0, pk1;
#pragma unroll
            for (int p = 0; p < 4; ++p) {
                asm("v_cvt_pk_bf16_f32 %0, %1, %2"
                    : "=v"(pk0.u[p]) : "v"(ex0[2 * p]), "v"(ex0[2 * p + 1]));
                asm("v_cvt_pk_bf16_f32 %0, %1, %2"
                    : "=v"(pk1.u[p]) : "v"(ex1[2 * p]), "v"(ex1[2 * p + 1]));
            }
            short8 af0 = pk0.s8, af1 = pk1.s8;
            accd0 = __builtin_amdgcn_mfma_f32_16x16x32_bf16(af0, ones, accd0, 0, 0, 0);
            accd1 = __builtin_amdgcn_mfma_f32_16x16x32_bf16(af1, ones, accd1, 0, 0, 0);
            int jb = kk * 4 + g;
#pragma unroll
            for (int nn = 0; nn < 4; ++nn) {
                int c = nn * 16 + lr;
                short8 bf0 = *(const short8*)(buf + c * 128 + ((jb ^ (c & 7)) << 4));
                acc0[nn] = __builtin_amdgcn_mfma_f32_16x16x32_bf16(af0, bf0, acc0[nn], 0, 0, 0);
                int c2 = 64 + nn * 16 + lr;
                short8 bf1 = *(const short8*)(buf + c2 * 128 + ((jb ^ (c2 & 7)) << 4));
                acc1[nn] = __builtin_amdgcn_mfma_f32_16x16x32_bf16(af1, bf1, acc1[nn], 0, 0, 0);
            }
        }
    }

    size_t obase = ((size_t)sj * R_ + (size_t)b * N_) * 256;
#pragma unroll
    for (int r = 0; r < 4; ++r) {
        int row = i_base + w * 16 + g * 4 + r;
        size_t rb = obase + (size_t)row * 256 + hc + lr;
#pragma unroll
        for (int nn = 0; nn < 4; ++nn) {
            opart[rb + nn * 16] = f2bf(acc0[nn][r]);
            opart[rb + 64 + nn * 16] = f2bf(acc1[nn][r]);
        }
        if (lr == 0) {
            dpart[(sj * R_ + b * N_ + row) * 4 + h0] = accd0[r];
            dpart[(sj * R_ + b * N_ + row) * 4 + h0 + 1] = accd1[r];
        }
    }
}

// ---------------------------------------------------------------------------
extern "C" void kernel_launch(void* const* d_in, const int* in_sizes, int n_in,
                              void* d_out, int out_size, void* d_ws, size_t ws_size,
                              hipStream_t stream) {
    const float* lat    = (const float*)d_in[0];
    const float* xc     = (const float*)d_in[1];
    const float* emb    = (const float*)d_in[2];
    const float* in_W   = (const float*)d_in[3];
    const float* in_b   = (const float*)d_in[4];
    const float* val_W  = (const float*)d_in[5];
    const float* val_b  = (const float*)d_in[6];
    const float* attn_W = (const float*)d_in[7];
    const float* attn_b = (const float*)d_in[8];
    const float* ln1_g  = (const float*)d_in[9];
    const float* ln1_b  = (const float*)d_in[10];
    const float* ln2_g  = (const float*)d_in[11];
    const float* ln2_b  = (const float*)d_in[12];
    const float* ffn_W1 = (const float*)d_in[13];
    const float* ffn_b1 = (const float*)d_in[14];
    const float* ffn_W2 = (const float*)d_in[15];
    const float* ffn_b2 = (const float*)d_in[16];
    const float* out_W1 = (const float*)d_in[17];
    const float* out_b1 = (const float*)d_in[18];
    const float* out_W2 = (const float*)d_in[19];
    const float* out_b2 = (const float*)d_in[20];

    char* W = (char*)d_ws;
    float*  feats  = (float*)W;                                // 8 MB
    ushort* featsb = (ushort*)(W + (8u << 20));                // 4 MB
    ushort* Vt     = (ushort*)(W + (12u << 20));               // 4 MB
    ushort* wp     = (ushort*)(W + (16u << 20));               // 3.2 MB
    ushort* opart  = (ushort*)(W + (20u << 20));               // 16 MB [4][R][256]
    float*  dpart  = (float*)(W + (36u << 20));                // 512 KB [4][R][4]
    ushort* Wvt  = wp;
    ushort* Wat  = wp + 262144;
    ushort* W1t  = wp + 524288;
    ushort* W2t  = wp + 1048576;
    ushort* Wo1t = wp + 1572864;

    pack_weights<<<6400, 256, 0, stream>>>(val_W, attn_W, ffn_W1, ffn_W2, out_W1, wp);
    input_mlp<<<R_ / 8, 256, 0, stream>>>(xc, emb, lat, in_W, in_b, feats, featsb);

    for (int l = 0; l < LAYERS_; ++l) {
        gemmM<256, 256, 3><<<dim3(R_ / 16, 1), 256, 0, stream>>>(
            featsb, Wvt + l * 65536, val_b + l * 256,
            nullptr, nullptr, nullptr, Vt, nullptr);
        attn_mfma<<<1024, 256, 0, stream>>>(xc, Vt, opart, dpart);
        gemmA<<<R_ / 16, 256, 0, stream>>>(
            opart, dpart, Wat + l * 65536, attn_b + l * 256,
            feats, ln1_g + l * 256, ln1_b + l * 256, featsb, feats);
        gemmF<<<R_ / 16, 256, 0, stream>>>(
            featsb, W1t + l * 131072, ffn_b1 + l * 512,
            W2t + l * 131072, ffn_b2 + l * 256,
            feats, ln2_g + l * 256, ln2_b + l * 256, featsb, feats);
    }

    gemmM<256, 256, 4><<<dim3(R_ / 16, 1), 256, 0, stream>>>(
        featsb, Wo1t, out_b1, out_W2, out_b2, nullptr, nullptr, (float*)d_out);
}